// Round 1
// baseline (709.019 us; speedup 1.0000x reference)
//
#include <hip/hip_runtime.h>

#define N_NODES 50000
#define N_EDGES 800000
#define ET (N_EDGES + N_NODES)   // edges + self loops = 850000
#define HID 128
#define HEADS 3
#define OPH 43
#define MID 129                  // HEADS*OPH
#define OUTC 6

__device__ __forceinline__ float lrelu(float x) { return x > 0.f ? x : 0.2f * x; }

// ---------------- CSR build ----------------

__global__ void count_kernel(const int* __restrict__ dst, int* __restrict__ cnt) {
    int e = blockIdx.x * blockDim.x + threadIdx.x;
    if (e >= ET) return;
    int d = (e < N_EDGES) ? dst[e] : (e - N_EDGES);
    atomicAdd(&cnt[d], 1);
}

// single-block exclusive scan (1024 threads, wave-scan + 16-partial scan per tile)
__global__ void scan_kernel(const int* __restrict__ cnt, int* __restrict__ row,
                            int* __restrict__ cursor) {
    __shared__ int wsum[16];
    __shared__ int carry_s;
    int tid  = threadIdx.x;
    int lane = tid & 63;
    int wv   = tid >> 6;
    if (tid == 0) carry_s = 0;
    __syncthreads();
    for (int base = 0; base < N_NODES; base += 1024) {
        int idx = base + tid;
        int v = (idx < N_NODES) ? cnt[idx] : 0;
        int x = v;
#pragma unroll
        for (int off = 1; off < 64; off <<= 1) {
            int t = __shfl_up(x, off, 64);
            if (lane >= off) x += t;
        }
        if (lane == 63) wsum[wv] = x;
        __syncthreads();
        if (wv == 0) {
            int w = (lane < 16) ? wsum[lane] : 0;
#pragma unroll
            for (int off = 1; off < 16; off <<= 1) {
                int t = __shfl_up(w, off, 64);
                if (lane >= off) w += t;
            }
            if (lane < 16) wsum[lane] = w;  // inclusive per-wave sums
        }
        __syncthreads();
        int wexcl = (wv == 0) ? 0 : wsum[wv - 1];
        int total = wsum[15];
        int c0    = carry_s;
        __syncthreads();
        int excl = c0 + wexcl + x - v;
        if (idx < N_NODES) { row[idx] = excl; cursor[idx] = excl; }
        if (tid == 0) carry_s = c0 + total;
        __syncthreads();
    }
    if (threadIdx.x == 0) row[N_NODES] = carry_s;
}

__global__ void scatter_kernel(const int* __restrict__ src, const int* __restrict__ dst,
                               int* __restrict__ cursor, int* __restrict__ csr_src) {
    int e = blockIdx.x * blockDim.x + threadIdx.x;
    if (e >= ET) return;
    int s, d;
    if (e < N_EDGES) { s = src[e]; d = dst[e]; }
    else             { s = d = e - N_EDGES; }
    int p = atomicAdd(&cursor[d], 1);
    csr_src[p] = s;
}

// ---------------- GEMM (fp32 vector ALU) ----------------
// block = 256 threads = 4 waves; 8 rows/wave (32 rows/block); lane owns cols {lane, lane+64, ...}
template <int K, int HC>
__global__ void gemm_kernel(const float* __restrict__ X, const float* __restrict__ W,
                            float* __restrict__ Hout, int nrows) {
    constexpr int SLOTS = (HC + 63) / 64;
    constexpr int ROWS  = 32;
    __shared__ float xs[ROWS * K];
    int tid  = threadIdx.x;
    int row0 = blockIdx.x * ROWS;
    int lim  = nrows - row0; if (lim > ROWS) lim = ROWS;
    int limf = lim * K;
    for (int idx = tid; idx < ROWS * K; idx += 256)
        xs[idx] = (idx < limf) ? X[(size_t)row0 * K + idx] : 0.f;
    __syncthreads();

    int wave = tid >> 6, lane = tid & 63;
    int cols[SLOTS];
#pragma unroll
    for (int j = 0; j < SLOTS; ++j) cols[j] = lane + 64 * j;
    float acc[8][SLOTS];
#pragma unroll
    for (int r = 0; r < 8; ++r)
#pragma unroll
        for (int j = 0; j < SLOTS; ++j) acc[r][j] = 0.f;

    for (int k = 0; k < K; ++k) {
        float wv[SLOTS];
#pragma unroll
        for (int j = 0; j < SLOTS; ++j)
            wv[j] = (cols[j] < HC) ? W[(size_t)k * HC + cols[j]] : 0.f;
#pragma unroll
        for (int r = 0; r < 8; ++r) {
            float xv = xs[(wave * 8 + r) * K + k];
#pragma unroll
            for (int j = 0; j < SLOTS; ++j) acc[r][j] += xv * wv[j];
        }
    }
#pragma unroll
    for (int r = 0; r < 8; ++r) {
        int rr = row0 + wave * 8 + r;
        if (rr < nrows) {
#pragma unroll
            for (int j = 0; j < SLOTS; ++j)
                if (cols[j] < HC) Hout[(size_t)rr * HC + cols[j]] = acc[r][j];
        }
    }
}

// layer-2 GEMM: [N,129] @ [129,6]
__global__ void gemm6_kernel(const float* __restrict__ X, const float* __restrict__ W,
                             float* __restrict__ Hout) {
    int n = blockIdx.x * blockDim.x + threadIdx.x;
    if (n >= N_NODES) return;
    const float* xr = X + (size_t)n * MID;
    float acc[OUTC] = {0.f, 0.f, 0.f, 0.f, 0.f, 0.f};
    for (int k = 0; k < MID; ++k) {
        float xv = xr[k];
#pragma unroll
        for (int c = 0; c < OUTC; ++c) acc[c] += xv * W[k * OUTC + c];
    }
#pragma unroll
    for (int c = 0; c < OUTC; ++c) Hout[(size_t)n * OUTC + c] = acc[c];
}

// ---------------- attention logits ----------------
template <int H, int C>
__global__ void alar_kernel(const float* __restrict__ hbuf, const float* __restrict__ as,
                            const float* __restrict__ ad, float* __restrict__ al,
                            float* __restrict__ ar) {
    int gid = blockIdx.x * blockDim.x + threadIdx.x;
    if (gid >= N_NODES * H) return;
    int n = gid / H, h = gid - n * H;
    const float* hp = hbuf + (size_t)n * (H * C) + h * C;
    float sl = 0.f, sr = 0.f;
#pragma unroll 1
    for (int c = 0; c < C; ++c) {
        float v = hp[c];
        sl += v * as[h * C + c];
        sr += v * ad[h * C + c];
    }
    al[gid] = sl;
    ar[gid] = sr;
}

// ---------------- edge softmax + aggregation: one wave per dst node ----------------
template <int H, int C, bool ACT>
__global__ void aggregate_kernel(const float* __restrict__ hbuf, const float* __restrict__ al,
                                 const float* __restrict__ ar, const int* __restrict__ rowp,
                                 const int* __restrict__ srcs, const float* __restrict__ bias,
                                 float* __restrict__ out) {
    constexpr int HC    = H * C;
    constexpr int SLOTS = (HC + 63) / 64;
    int lane = threadIdx.x & 63;
    int wid  = __builtin_amdgcn_readfirstlane((blockIdx.x << 2) | (threadIdx.x >> 6));
    if (wid >= N_NODES) return;

    int beg = rowp[wid], end = rowp[wid + 1];
    float ard[H];
#pragma unroll
    for (int h = 0; h < H; ++h) ard[h] = ar[wid * H + h];

    // pass A: per-head max over incoming edges
    float m[H];
#pragma unroll
    for (int h = 0; h < H; ++h) m[h] = -1e30f;
    for (int i = beg + lane; i < end; i += 64) {
        int s = srcs[i];
#pragma unroll
        for (int h = 0; h < H; ++h) {
            float e = lrelu(al[s * H + h] + ard[h]);
            m[h] = fmaxf(m[h], e);
        }
    }
#pragma unroll
    for (int off = 32; off; off >>= 1)
#pragma unroll
        for (int h = 0; h < H; ++h) m[h] = fmaxf(m[h], __shfl_xor(m[h], off, 64));

    // pass B: denom
    float ssum[H];
#pragma unroll
    for (int h = 0; h < H; ++h) ssum[h] = 0.f;
    for (int i = beg + lane; i < end; i += 64) {
        int s = srcs[i];
#pragma unroll
        for (int h = 0; h < H; ++h) {
            float e = lrelu(al[s * H + h] + ard[h]);
            ssum[h] += __expf(e - m[h]);
        }
    }
#pragma unroll
    for (int off = 32; off; off >>= 1)
#pragma unroll
        for (int h = 0; h < H; ++h) ssum[h] += __shfl_xor(ssum[h], off, 64);
    float dinv[H];
#pragma unroll
    for (int h = 0; h < H; ++h) dinv[h] = 1.f / (ssum[h] + 1e-16f);

    // lane->channel map
    int   mych[SLOTS], myhead[SLOTS];
    bool  valid[SLOTS];
#pragma unroll
    for (int j = 0; j < SLOTS; ++j) {
        mych[j]   = lane + 64 * j;
        valid[j]  = mych[j] < HC;
        myhead[j] = valid[j] ? mych[j] / C : 0;
    }

    // pass C: weighted accumulate (all lanes walk same edge; h[src] read coalesced)
    float acc[SLOTS];
#pragma unroll
    for (int j = 0; j < SLOTS; ++j) acc[j] = 0.f;
    for (int i = beg; i < end; ++i) {
        int s = srcs[i];
        float alpha[H];
#pragma unroll
        for (int h = 0; h < H; ++h) {
            float e  = lrelu(al[s * H + h] + ard[h]);
            alpha[h] = __expf(e - m[h]) * dinv[h];
        }
        const float* hr = hbuf + (size_t)s * HC;
#pragma unroll
        for (int j = 0; j < SLOTS; ++j)
            if (valid[j]) acc[j] += alpha[myhead[j]] * hr[mych[j]];
    }

    // epilogue: bias (+ optional leaky_relu), full overwrite of out row
#pragma unroll
    for (int j = 0; j < SLOTS; ++j) {
        if (valid[j]) {
            float v = acc[j] + bias[mych[j]];
            if (ACT) v = lrelu(v);
            out[(size_t)wid * HC + mych[j]] = v;
        }
    }
}

// ---------------- launch ----------------

extern "C" void kernel_launch(void* const* d_in, const int* in_sizes, int n_in,
                              void* d_out, int out_size, void* d_ws, size_t ws_size,
                              hipStream_t stream) {
    const float* x   = (const float*)d_in[0];
    const int*   ei  = (const int*)d_in[1];
    const float* W0  = (const float*)d_in[2];
    const float* a0s = (const float*)d_in[3];
    const float* a0d = (const float*)d_in[4];
    const float* b0  = (const float*)d_in[5];
    const float* W1  = (const float*)d_in[6];
    const float* a1s = (const float*)d_in[7];
    const float* a1d = (const float*)d_in[8];
    const float* b1  = (const float*)d_in[9];
    const float* W2  = (const float*)d_in[10];
    const float* a2s = (const float*)d_in[11];
    const float* a2d = (const float*)d_in[12];
    const float* b2  = (const float*)d_in[13];
    float* out = (float*)d_out;

    char* p = (char*)d_ws;
    auto take = [&](size_t bytes) -> void* {
        void* r = (void*)p;
        p += (bytes + 255) & ~(size_t)255;
        return r;
    };
    int*   cnt     = (int*)take((size_t)N_NODES * 4);
    int*   rowp    = (int*)take((size_t)(N_NODES + 1) * 4);
    int*   cursor  = (int*)take((size_t)N_NODES * 4);
    int*   csr_src = (int*)take((size_t)ET * 4);
    float* al      = (float*)take((size_t)N_NODES * HEADS * 4);
    float* ar      = (float*)take((size_t)N_NODES * HEADS * 4);
    float* hbuf    = (float*)take((size_t)N_NODES * MID * 4);
    float* obuf    = (float*)take((size_t)N_NODES * MID * 4);

    const int* esrc = ei;
    const int* edst = ei + N_EDGES;

    // CSR by destination (self-loops appended)
    hipMemsetAsync(cnt, 0, (size_t)N_NODES * 4, stream);
    count_kernel<<<(ET + 255) / 256, 256, 0, stream>>>(edst, cnt);
    scan_kernel<<<1, 1024, 0, stream>>>(cnt, rowp, cursor);
    scatter_kernel<<<(ET + 255) / 256, 256, 0, stream>>>(esrc, edst, cursor, csr_src);

    const int gemm_grid = (N_NODES + 31) / 32;
    const int agg_grid  = (N_NODES + 3) / 4;

    // layer 0
    gemm_kernel<HID, MID><<<gemm_grid, 256, 0, stream>>>(x, W0, hbuf, N_NODES);
    alar_kernel<HEADS, OPH><<<(N_NODES * HEADS + 255) / 256, 256, 0, stream>>>(hbuf, a0s, a0d, al, ar);
    aggregate_kernel<HEADS, OPH, true><<<agg_grid, 256, 0, stream>>>(hbuf, al, ar, rowp, csr_src, b0, obuf);

    // layer 1
    gemm_kernel<MID, MID><<<gemm_grid, 256, 0, stream>>>(obuf, W1, hbuf, N_NODES);
    alar_kernel<HEADS, OPH><<<(N_NODES * HEADS + 255) / 256, 256, 0, stream>>>(hbuf, a1s, a1d, al, ar);
    aggregate_kernel<HEADS, OPH, true><<<agg_grid, 256, 0, stream>>>(hbuf, al, ar, rowp, csr_src, b1, obuf);

    // layer 2 (heads=1, ch=6, no concat-act; bias only)
    gemm6_kernel<<<(N_NODES + 255) / 256, 256, 0, stream>>>(obuf, W2, hbuf);
    alar_kernel<1, OUTC><<<(N_NODES + 255) / 256, 256, 0, stream>>>(hbuf, a2s, a2d, al, ar);
    aggregate_kernel<1, OUTC, false><<<agg_grid, 256, 0, stream>>>(hbuf, al, ar, rowp, csr_src, b2, out);
}

// Round 2
// 526.410 us; speedup vs baseline: 1.3469x; 1.3469x over previous
//
#include <hip/hip_runtime.h>

#define N_NODES 50000
#define N_EDGES 800000
#define ET (N_EDGES + N_NODES)   // edges + self loops = 850000
#define HID 128
#define MID 129
#define OUTC 6

__device__ __forceinline__ float lrelu(float x) { return x > 0.f ? x : 0.2f * x; }

// ---------------- CSR build ----------------

__global__ void count_kernel(const int* __restrict__ dst, int* __restrict__ cnt) {
    int e = blockIdx.x * blockDim.x + threadIdx.x;
    if (e >= ET) return;
    int d = (e < N_EDGES) ? dst[e] : (e - N_EDGES);
    atomicAdd(&cnt[d], 1);
}

// single-block exclusive scan, 4 elements/thread (13 tiles of 4096)
__global__ void scan_kernel(const int* __restrict__ cnt, int* __restrict__ row,
                            int* __restrict__ cursor) {
    __shared__ int wsum[16];
    __shared__ int carry_s;
    int tid  = threadIdx.x;
    int lane = tid & 63;
    int wv   = tid >> 6;
    if (tid == 0) carry_s = 0;
    __syncthreads();
    for (int base = 0; base < N_NODES; base += 4096) {
        int i0 = base + tid * 4;
        int v0 = 0, v1 = 0, v2 = 0, v3 = 0;
        if (i0 + 3 < N_NODES) {
            const int4 q = *(const int4*)(cnt + i0);
            v0 = q.x; v1 = q.y; v2 = q.z; v3 = q.w;
        } else {
            if (i0     < N_NODES) v0 = cnt[i0];
            if (i0 + 1 < N_NODES) v1 = cnt[i0 + 1];
            if (i0 + 2 < N_NODES) v2 = cnt[i0 + 2];
            if (i0 + 3 < N_NODES) v3 = cnt[i0 + 3];
        }
        int t = v0 + v1 + v2 + v3;
        int x = t;
#pragma unroll
        for (int off = 1; off < 64; off <<= 1) {
            int sh = __shfl_up(x, off, 64);
            if (lane >= off) x += sh;
        }
        if (lane == 63) wsum[wv] = x;
        __syncthreads();
        if (wv == 0) {
            int w = (lane < 16) ? wsum[lane] : 0;
#pragma unroll
            for (int off = 1; off < 16; off <<= 1) {
                int sh = __shfl_up(w, off, 64);
                if (lane >= off) w += sh;
            }
            if (lane < 16) wsum[lane] = w;
        }
        __syncthreads();
        int wexcl = wv ? wsum[wv - 1] : 0;
        int total = wsum[15];
        int c0    = carry_s;
        __syncthreads();
        int e = c0 + wexcl + (x - t);
        if (i0     < N_NODES) { row[i0]     = e; cursor[i0]     = e; } e += v0;
        if (i0 + 1 < N_NODES) { row[i0 + 1] = e; cursor[i0 + 1] = e; } e += v1;
        if (i0 + 2 < N_NODES) { row[i0 + 2] = e; cursor[i0 + 2] = e; } e += v2;
        if (i0 + 3 < N_NODES) { row[i0 + 3] = e; cursor[i0 + 3] = e; }
        if (tid == 0) carry_s = c0 + total;
        __syncthreads();
    }
    if (tid == 0) row[N_NODES] = carry_s;
}

__global__ void scatter_kernel(const int* __restrict__ src, const int* __restrict__ dst,
                               int* __restrict__ cursor, int* __restrict__ csr_src) {
    int e = blockIdx.x * blockDim.x + threadIdx.x;
    if (e >= ET) return;
    int s, d;
    if (e < N_EDGES) { s = src[e]; d = dst[e]; }
    else             { s = d = e - N_EDGES; }
    int p = atomicAdd(&cursor[d], 1);
    csr_src[p] = s;
}

// ---------------- GEMM (fp32 vector ALU), split output Hm[N][128] + Hl[N] ----------------
// block = 256 = 4 waves; 8 rows/wave (32 rows/block); lane owns cols {lane, lane+64}; col 128 broadcast
template <int K>
__global__ void gemm_kernel(const float* __restrict__ X, const float* __restrict__ Xl,
                            const float* __restrict__ W, float* __restrict__ Hm,
                            float* __restrict__ Hl) {
    constexpr int ROWS = 32;
    __shared__ float xs[ROWS * K];
    int tid  = threadIdx.x;
    int row0 = blockIdx.x * ROWS;
    for (int idx = tid; idx < ROWS * K; idx += 256) {
        int r = idx / K;
        int k = idx - r * K;
        int row = row0 + r;
        float v = 0.f;
        if (row < N_NODES)
            v = (K == 129 && k == 128) ? Xl[row] : X[((size_t)row << 7) + k];
        xs[idx] = v;
    }
    __syncthreads();

    int wave = tid >> 6, lane = tid & 63;
    float acc[8][3];
#pragma unroll
    for (int r = 0; r < 8; ++r) { acc[r][0] = 0.f; acc[r][1] = 0.f; acc[r][2] = 0.f; }

    const float* xrow = xs + wave * 8 * K;
    for (int k = 0; k < K; ++k) {
        float w0 = W[k * MID + lane];
        float w1 = W[k * MID + 64 + lane];
        float w2 = W[k * MID + 128];   // broadcast
#pragma unroll
        for (int r = 0; r < 8; ++r) {
            float xv = xrow[r * K + k];
            acc[r][0] += xv * w0;
            acc[r][1] += xv * w1;
            acc[r][2] += xv * w2;
        }
    }
#pragma unroll
    for (int r = 0; r < 8; ++r) {
        int row = row0 + wave * 8 + r;
        if (row < N_NODES) {
            Hm[((size_t)row << 7) + lane]      = acc[r][0];
            Hm[((size_t)row << 7) + 64 + lane] = acc[r][1];
            if (lane == 0) Hl[row] = acc[r][2];
        }
    }
}

// ---------------- attention logits: wave per node, float2 loads + butterfly ----------------
__global__ void alar_kernel(const float* __restrict__ Hm, const float* __restrict__ Hl,
                            const float* __restrict__ asf, const float* __restrict__ adf,
                            float* __restrict__ al, float* __restrict__ ar) {
    int lane = threadIdx.x & 63;
    int wid  = blockIdx.x * 4 + (threadIdx.x >> 6);
    if (wid >= N_NODES) return;
    int c0 = 2 * lane, c1 = c0 + 1;
    int h0 = c0 / 43, h1 = c1 / 43;
    float as0 = asf[c0], as1 = asf[c1], ad0 = adf[c0], ad1 = adf[c1];
    float as128 = asf[128], ad128 = adf[128];

    float2 hv  = *(const float2*)(Hm + ((size_t)wid << 7) + c0);
    float h128 = Hl[wid];

    float plx = hv.x * as0, ply = hv.y * as1;
    float prx = hv.x * ad0, pry = hv.y * ad1;
    float pl[3], pr[3];
#pragma unroll
    for (int h = 0; h < 3; ++h) {
        pl[h] = (h0 == h ? plx : 0.f) + (h1 == h ? ply : 0.f);
        pr[h] = (h0 == h ? prx : 0.f) + (h1 == h ? pry : 0.f);
    }
    float m0 = (lane == 0) ? 1.f : 0.f;
    pl[2] += m0 * h128 * as128;
    pr[2] += m0 * h128 * ad128;
#pragma unroll
    for (int off = 32; off; off >>= 1) {
#pragma unroll
        for (int h = 0; h < 3; ++h) {
            pl[h] += __shfl_xor(pl[h], off, 64);
            pr[h] += __shfl_xor(pr[h], off, 64);
        }
    }
    if (lane == 0) {
#pragma unroll
        for (int h = 0; h < 3; ++h) {
            al[wid * 3 + h] = pl[h];
            ar[wid * 3 + h] = pr[h];
        }
    }
}

// ---------------- fused single-sweep softmax + aggregation (129 ch, 3 heads) ----------------
template <bool ACT>
__global__ void agg129_kernel(const float* __restrict__ Hm, const float* __restrict__ Hl,
                              const float* __restrict__ al, const float* __restrict__ ar,
                              const int* __restrict__ rowp, const int* __restrict__ srcs,
                              const float* __restrict__ bias, float* __restrict__ Om,
                              float* __restrict__ Ol) {
    __shared__ float4 exs[4][64];
    int lane = threadIdx.x & 63;
    int wv   = threadIdx.x >> 6;
    int wid  = blockIdx.x * 4 + wv;
    if (wid >= N_NODES) return;

    int beg = rowp[wid], end = rowp[wid + 1];
    float ard0 = ar[wid * 3], ard1 = ar[wid * 3 + 1], ard2 = ar[wid * 3 + 2];

    int c0 = 2 * lane;
    int h0 = c0 / 43, h1 = (c0 + 1) / 43;

    float2 acc = {0.f, 0.f};
    float  acc128 = 0.f;
    float  s0 = 0.f, s1 = 0.f, s2 = 0.f;
    float4* exw = exs[wv];

    for (int base = beg; base < end; base += 64) {
        int i = base + lane;
        float e0 = 0.f, e1 = 0.f, e2 = 0.f;
        int s = 0;
        if (i < end) {
            s = srcs[i];
            const float* ap = al + s * 3;
            e0 = __expf(lrelu(ap[0] + ard0));
            e1 = __expf(lrelu(ap[1] + ard1));
            e2 = __expf(lrelu(ap[2] + ard2));
            s0 += e0; s1 += e1; s2 += e2;
        }
        exw[lane] = make_float4(e0, e1, e2, __int_as_float(s));
        int cnt = end - base; if (cnt > 64) cnt = 64;
        for (int t = 0; t < cnt; ++t) {
            float4 ed = exw[t];                       // uniform ds_read_b128 broadcast
            int ss = __float_as_int(ed.w);
            const float* hr = Hm + ((size_t)ss << 7);
            float2 hv = *(const float2*)(hr + c0);    // coalesced 512B gather
            float h128 = Hl[ss];                      // broadcast, L2-resident
            float w0 = (h0 == 0) ? ed.x : ((h0 == 1) ? ed.y : ed.z);
            float w1 = (h1 == 0) ? ed.x : ((h1 == 1) ? ed.y : ed.z);
            acc.x  += w0 * hv.x;
            acc.y  += w1 * hv.y;
            acc128 += ed.z * h128;
        }
    }
#pragma unroll
    for (int off = 32; off; off >>= 1) {
        s0 += __shfl_xor(s0, off, 64);
        s1 += __shfl_xor(s1, off, 64);
        s2 += __shfl_xor(s2, off, 64);
    }
    float d0 = 1.f / (s0 + 1e-16f);
    float d1 = 1.f / (s1 + 1e-16f);
    float d2 = 1.f / (s2 + 1e-16f);
    float dv0 = (h0 == 0) ? d0 : ((h0 == 1) ? d1 : d2);
    float dv1 = (h1 == 0) ? d0 : ((h1 == 1) ? d1 : d2);
    float ox = acc.x * dv0 + bias[c0];
    float oy = acc.y * dv1 + bias[c0 + 1];
    if (ACT) { ox = lrelu(ox); oy = lrelu(oy); }
    float2 o2 = {ox, oy};
    *(float2*)(Om + ((size_t)wid << 7) + c0) = o2;
    if (lane == 0) {
        float o128 = acc128 * d2 + bias[128];
        if (ACT) o128 = lrelu(o128);
        Ol[wid] = o128;
    }
}

// ---------------- layer 2: fused GEMM (129->6) + logits, wave per node ----------------
__global__ void layer2_node_kernel(const float* __restrict__ Om, const float* __restrict__ Ol,
                                   const float* __restrict__ W2, const float* __restrict__ a2s,
                                   const float* __restrict__ a2d, float* __restrict__ H2,
                                   float* __restrict__ al2, float* __restrict__ ar2) {
    int lane = threadIdx.x & 63;
    int wid  = blockIdx.x * 4 + (threadIdx.x >> 6);
    if (wid >= N_NODES) return;
    int c0 = 2 * lane;
    float2 xv  = *(const float2*)(Om + ((size_t)wid << 7) + c0);
    float x128 = Ol[wid];
    const float* w0p = W2 + c0 * OUTC;
    const float* w1p = W2 + (c0 + 1) * OUTC;
    float m = (lane == 0) ? x128 : 0.f;
    float p[OUTC];
#pragma unroll
    for (int c = 0; c < OUTC; ++c)
        p[c] = xv.x * w0p[c] + xv.y * w1p[c] + m * W2[128 * OUTC + c];
#pragma unroll
    for (int off = 32; off; off >>= 1)
#pragma unroll
        for (int c = 0; c < OUTC; ++c) p[c] += __shfl_xor(p[c], off, 64);
    float sl = 0.f, sr = 0.f;
#pragma unroll
    for (int c = 0; c < OUTC; ++c) { sl += p[c] * a2s[c]; sr += p[c] * a2d[c]; }
    if (lane == 0) {
#pragma unroll
        for (int c = 0; c < OUTC; ++c) H2[wid * OUTC + c] = p[c];
        al2[wid] = sl;
        ar2[wid] = sr;
    }
}

// ---------------- layer 2 aggregate (1 head, 6 ch) ----------------
__global__ void agg6_kernel(const float* __restrict__ H2, const float* __restrict__ al2,
                            const float* __restrict__ ar2, const int* __restrict__ rowp,
                            const int* __restrict__ srcs, const float* __restrict__ b2,
                            float* __restrict__ out) {
    __shared__ float2 exs[4][64];
    int lane = threadIdx.x & 63;
    int wv   = threadIdx.x >> 6;
    int wid  = blockIdx.x * 4 + wv;
    if (wid >= N_NODES) return;
    int beg = rowp[wid], end = rowp[wid + 1];
    float ard = ar2[wid];
    float ssum = 0.f, acc = 0.f;
    int myc = (lane < OUTC) ? lane : 0;
    float2* exw = exs[wv];
    for (int base = beg; base < end; base += 64) {
        int i = base + lane;
        float ex = 0.f;
        int s = 0;
        if (i < end) {
            s = srcs[i];
            ex = __expf(lrelu(al2[s] + ard));
            ssum += ex;
        }
        exw[lane] = make_float2(ex, __int_as_float(s));
        int cnt = end - base; if (cnt > 64) cnt = 64;
        for (int t = 0; t < cnt; ++t) {
            float2 ed = exw[t];
            int ss = __float_as_int(ed.y);
            float hv = H2[ss * OUTC + myc];
            acc += ed.x * hv;
        }
    }
#pragma unroll
    for (int off = 32; off; off >>= 1) ssum += __shfl_xor(ssum, off, 64);
    float dinv = 1.f / (ssum + 1e-16f);
    if (lane < OUTC) out[(size_t)wid * OUTC + lane] = acc * dinv + b2[lane];
}

// ---------------- launch ----------------

extern "C" void kernel_launch(void* const* d_in, const int* in_sizes, int n_in,
                              void* d_out, int out_size, void* d_ws, size_t ws_size,
                              hipStream_t stream) {
    const float* x   = (const float*)d_in[0];
    const int*   ei  = (const int*)d_in[1];
    const float* W0  = (const float*)d_in[2];
    const float* a0s = (const float*)d_in[3];
    const float* a0d = (const float*)d_in[4];
    const float* b0  = (const float*)d_in[5];
    const float* W1  = (const float*)d_in[6];
    const float* a1s = (const float*)d_in[7];
    const float* a1d = (const float*)d_in[8];
    const float* b1  = (const float*)d_in[9];
    const float* W2  = (const float*)d_in[10];
    const float* a2s = (const float*)d_in[11];
    const float* a2d = (const float*)d_in[12];
    const float* b2  = (const float*)d_in[13];
    float* out = (float*)d_out;

    char* p = (char*)d_ws;
    auto take = [&](size_t bytes) -> void* {
        void* r = (void*)p;
        p += (bytes + 255) & ~(size_t)255;
        return r;
    };
    int*   cnt     = (int*)take((size_t)N_NODES * 4);
    int*   rowp    = (int*)take((size_t)(N_NODES + 1) * 4);
    int*   cursor  = (int*)take((size_t)N_NODES * 4);
    int*   csr_src = (int*)take((size_t)ET * 4);
    float* al      = (float*)take((size_t)N_NODES * 3 * 4);
    float* ar      = (float*)take((size_t)N_NODES * 3 * 4);
    float* Hm      = (float*)take((size_t)N_NODES * 128 * 4);
    float* Hl      = (float*)take((size_t)N_NODES * 4);
    float* Om      = (float*)take((size_t)N_NODES * 128 * 4);
    float* Ol      = (float*)take((size_t)N_NODES * 4);

    const int* esrc = ei;
    const int* edst = ei + N_EDGES;

    hipMemsetAsync(cnt, 0, (size_t)N_NODES * 4, stream);
    count_kernel<<<(ET + 255) / 256, 256, 0, stream>>>(edst, cnt);
    scan_kernel<<<1, 1024, 0, stream>>>(cnt, rowp, cursor);
    scatter_kernel<<<(ET + 255) / 256, 256, 0, stream>>>(esrc, edst, cursor, csr_src);

    const int gemm_grid = (N_NODES + 31) / 32;
    const int node_grid = (N_NODES + 3) / 4;

    // layer 0
    gemm_kernel<128><<<gemm_grid, 256, 0, stream>>>(x, x, W0, Hm, Hl);
    alar_kernel<<<node_grid, 256, 0, stream>>>(Hm, Hl, a0s, a0d, al, ar);
    agg129_kernel<true><<<node_grid, 256, 0, stream>>>(Hm, Hl, al, ar, rowp, csr_src, b0, Om, Ol);

    // layer 1
    gemm_kernel<129><<<gemm_grid, 256, 0, stream>>>(Om, Ol, W1, Hm, Hl);
    alar_kernel<<<node_grid, 256, 0, stream>>>(Hm, Hl, a1s, a1d, al, ar);
    agg129_kernel<true><<<node_grid, 256, 0, stream>>>(Hm, Hl, al, ar, rowp, csr_src, b1, Om, Ol);

    // layer 2: fused gemm+logits (H2 reuses Hm; al/ar reused as al2/ar2), then aggregate
    layer2_node_kernel<<<node_grid, 256, 0, stream>>>(Om, Ol, W2, a2s, a2d, Hm, al, ar);
    agg6_kernel<<<node_grid, 256, 0, stream>>>(Hm, al, ar, rowp, csr_src, b2, out);
}

// Round 3
// 496.662 us; speedup vs baseline: 1.4276x; 1.0599x over previous
//
#include <hip/hip_runtime.h>

#define N_NODES 50000
#define N_EDGES 800000
#define ET (N_EDGES + N_NODES)   // edges + self loops = 850000
#define MID 129
#define OUTC 6

__device__ __forceinline__ float lrelu(float x) { return x > 0.f ? x : 0.2f * x; }

// ---------------- CSR build ----------------

__global__ void count_kernel(const int* __restrict__ dst, int* __restrict__ cnt) {
    int e = blockIdx.x * blockDim.x + threadIdx.x;
    if (e >= ET) return;
    int d = (e < N_EDGES) ? dst[e] : (e - N_EDGES);
    atomicAdd(&cnt[d], 1);
}

// single-block exclusive scan, 4 elements/thread (13 tiles of 4096)
__global__ void scan_kernel(const int* __restrict__ cnt, int* __restrict__ row,
                            int* __restrict__ cursor) {
    __shared__ int wsum[16];
    __shared__ int carry_s;
    int tid  = threadIdx.x;
    int lane = tid & 63;
    int wv   = tid >> 6;
    if (tid == 0) carry_s = 0;
    __syncthreads();
    for (int base = 0; base < N_NODES; base += 4096) {
        int i0 = base + tid * 4;
        int v0 = 0, v1 = 0, v2 = 0, v3 = 0;
        if (i0 + 3 < N_NODES) {
            const int4 q = *(const int4*)(cnt + i0);
            v0 = q.x; v1 = q.y; v2 = q.z; v3 = q.w;
        } else {
            if (i0     < N_NODES) v0 = cnt[i0];
            if (i0 + 1 < N_NODES) v1 = cnt[i0 + 1];
            if (i0 + 2 < N_NODES) v2 = cnt[i0 + 2];
            if (i0 + 3 < N_NODES) v3 = cnt[i0 + 3];
        }
        int t = v0 + v1 + v2 + v3;
        int x = t;
#pragma unroll
        for (int off = 1; off < 64; off <<= 1) {
            int sh = __shfl_up(x, off, 64);
            if (lane >= off) x += sh;
        }
        if (lane == 63) wsum[wv] = x;
        __syncthreads();
        if (wv == 0) {
            int w = (lane < 16) ? wsum[lane] : 0;
#pragma unroll
            for (int off = 1; off < 16; off <<= 1) {
                int sh = __shfl_up(w, off, 64);
                if (lane >= off) w += sh;
            }
            if (lane < 16) wsum[lane] = w;
        }
        __syncthreads();
        int wexcl = wv ? wsum[wv - 1] : 0;
        int total = wsum[15];
        int c0    = carry_s;
        __syncthreads();
        int e = c0 + wexcl + (x - t);
        if (i0     < N_NODES) { row[i0]     = e; cursor[i0]     = e; } e += v0;
        if (i0 + 1 < N_NODES) { row[i0 + 1] = e; cursor[i0 + 1] = e; } e += v1;
        if (i0 + 2 < N_NODES) { row[i0 + 2] = e; cursor[i0 + 2] = e; } e += v2;
        if (i0 + 3 < N_NODES) { row[i0 + 3] = e; cursor[i0 + 3] = e; }
        if (tid == 0) carry_s = c0 + total;
        __syncthreads();
    }
    if (tid == 0) row[N_NODES] = carry_s;
}

__global__ void scatter_kernel(const int* __restrict__ src, const int* __restrict__ dst,
                               int* __restrict__ cursor, int* __restrict__ csr_src) {
    int e = blockIdx.x * blockDim.x + threadIdx.x;
    if (e >= ET) return;
    int s, d;
    if (e < N_EDGES) { s = src[e]; d = dst[e]; }
    else             { s = d = e - N_EDGES; }
    int p = atomicAdd(&cursor[d], 1);
    csr_src[p] = s;
}

// ---------------- W pre-pad: [K][129] -> [K][132] (8B-aligned float2 cols) + col-128 extract ----
__global__ void padw_kernel(const float* __restrict__ W, float* __restrict__ Wp,
                            float* __restrict__ wcol, int K) {
    int i = blockIdx.x * blockDim.x + threadIdx.x;
    if (i >= K * 132) return;
    int k = i / 132, c = i - k * 132;
    float v = (c < MID) ? W[k * MID + c] : 0.f;
    Wp[i] = v;
    if (c == 128) wcol[k] = v;
}

// ---------------- GEMM v2 (fp32 vector ALU) ----------------
// block = 256 = 4 waves; 8 rows/wave; lane owns output cols {2l, 2l+1}; col 128 via butterfly epilogue
template <int K>
__global__ void gemm_kernel(const float* __restrict__ X, const float* __restrict__ Xl,
                            const float* __restrict__ Wp, const float* __restrict__ wcol,
                            float* __restrict__ Hm, float* __restrict__ Hl) {
    __shared__ float xs[32 * 132];
    __shared__ float Wc[132];
    int tid  = threadIdx.x;
    int row0 = blockIdx.x * 32;
    {
        int k = tid & 127;
        for (int rr = tid >> 7; rr < 32; rr += 2) {
            int row = row0 + rr;
            xs[rr * 132 + k] = (row < N_NODES) ? X[((size_t)row << 7) + k] : 0.f;
            if (k == 0)
                xs[rr * 132 + 128] = (K == 129 && row < N_NODES) ? Xl[row] : 0.f;
        }
        if (tid < K) Wc[tid] = wcol[tid];
    }
    __syncthreads();

    int wave = tid >> 6, lane = tid & 63;
    int c0 = 2 * lane;
    const float* xbase = xs + wave * 8 * 132;
    float2 acc[8];
#pragma unroll
    for (int r = 0; r < 8; ++r) acc[r] = make_float2(0.f, 0.f);

    for (int k0 = 0; k0 < 128; k0 += 4) {
        float2 wv[4];
#pragma unroll
        for (int j = 0; j < 4; ++j)
            wv[j] = *(const float2*)(Wp + (k0 + j) * 132 + c0);
#pragma unroll
        for (int r = 0; r < 8; ++r) {
            float4 xq = *(const float4*)(xbase + r * 132 + k0);
            acc[r].x += xq.x * wv[0].x; acc[r].y += xq.x * wv[0].y;
            acc[r].x += xq.y * wv[1].x; acc[r].y += xq.y * wv[1].y;
            acc[r].x += xq.z * wv[2].x; acc[r].y += xq.z * wv[2].y;
            acc[r].x += xq.w * wv[3].x; acc[r].y += xq.w * wv[3].y;
        }
    }
    if (K == 129) {
        float2 wv = *(const float2*)(Wp + 128 * 132 + c0);
#pragma unroll
        for (int r = 0; r < 8; ++r) {
            float xv = xbase[r * 132 + 128];
            acc[r].x += xv * wv.x; acc[r].y += xv * wv.y;
        }
    }
#pragma unroll
    for (int r = 0; r < 8; ++r) {
        int row = row0 + wave * 8 + r;
        if (row < N_NODES)
            *(float2*)(Hm + ((size_t)row << 7) + c0) = acc[r];
    }
    // col 128: lanes split k, butterfly-sum per row
#pragma unroll
    for (int r = 0; r < 8; ++r) {
        const float* xr = xbase + r * 132;
        float p = xr[lane] * Wc[lane] + xr[64 + lane] * Wc[64 + lane];
        if (K == 129 && lane == 0) p += xr[128] * Wc[128];
#pragma unroll
        for (int off = 32; off; off >>= 1) p += __shfl_xor(p, off, 64);
        int row = row0 + wave * 8 + r;
        if (lane == 0 && row < N_NODES) Hl[row] = p;
    }
}

// ---------------- attention logits: wave per node ----------------
__global__ void alar_kernel(const float* __restrict__ Hm, const float* __restrict__ Hl,
                            const float* __restrict__ asf, const float* __restrict__ adf,
                            float* __restrict__ al, float* __restrict__ ar) {
    int lane = threadIdx.x & 63;
    int wid  = blockIdx.x * 4 + (threadIdx.x >> 6);
    if (wid >= N_NODES) return;
    int c0 = 2 * lane, c1 = c0 + 1;
    int h0 = c0 / 43, h1 = c1 / 43;
    float as0 = asf[c0], as1 = asf[c1], ad0 = adf[c0], ad1 = adf[c1];
    float as128 = asf[128], ad128 = adf[128];

    float2 hv  = *(const float2*)(Hm + ((size_t)wid << 7) + c0);
    float h128 = Hl[wid];

    float plx = hv.x * as0, ply = hv.y * as1;
    float prx = hv.x * ad0, pry = hv.y * ad1;
    float pl[3], pr[3];
#pragma unroll
    for (int h = 0; h < 3; ++h) {
        pl[h] = (h0 == h ? plx : 0.f) + (h1 == h ? ply : 0.f);
        pr[h] = (h0 == h ? prx : 0.f) + (h1 == h ? pry : 0.f);
    }
    float m0 = (lane == 0) ? 1.f : 0.f;
    pl[2] += m0 * h128 * as128;
    pr[2] += m0 * h128 * ad128;
#pragma unroll
    for (int off = 32; off; off >>= 1) {
#pragma unroll
        for (int h = 0; h < 3; ++h) {
            pl[h] += __shfl_xor(pl[h], off, 64);
            pr[h] += __shfl_xor(pr[h], off, 64);
        }
    }
    if (lane == 0) {
#pragma unroll
        for (int h = 0; h < 3; ++h) {
            al[wid * 3 + h] = pl[h];
            ar[wid * 3 + h] = pr[h];
        }
    }
}

// ---------------- fused softmax + aggregation (129 ch, 3 heads), 2 edges/iter ----------------
template <bool ACT>
__global__ void agg129_kernel(const float* __restrict__ Hm, const float* __restrict__ Hl,
                              const float* __restrict__ al, const float* __restrict__ ar,
                              const int* __restrict__ rowp, const int* __restrict__ srcs,
                              const float* __restrict__ bias, float* __restrict__ Om,
                              float* __restrict__ Ol) {
    __shared__ float4 exs[4][64];
    int lane = threadIdx.x & 63;
    int wv   = threadIdx.x >> 6;
    int wid  = blockIdx.x * 4 + wv;
    if (wid >= N_NODES) return;

    int beg = rowp[wid], end = rowp[wid + 1];
    float ard0 = ar[wid * 3], ard1 = ar[wid * 3 + 1], ard2 = ar[wid * 3 + 2];

    int half = lane >> 5;       // which edge of the pair
    int q    = lane & 31;
    int c0   = 4 * q;           // this lane's 4 channels

    float4 acc = {0.f, 0.f, 0.f, 0.f};
    float  acc128 = 0.f;
    float  s0 = 0.f, s1 = 0.f, s2 = 0.f;
    float4* exw = exs[wv];

    for (int base = beg; base < end; base += 64) {
        int i = base + lane;
        float e0 = 0.f, e1 = 0.f, e2 = 0.f;
        int s = 0;
        if (i < end) {
            s = srcs[i];
            const float* ap = al + s * 3;
            e0 = __expf(lrelu(ap[0] + ard0));
            e1 = __expf(lrelu(ap[1] + ard1));
            e2 = __expf(lrelu(ap[2] + ard2));
            s0 += e0; s1 += e1; s2 += e2;
        }
        exw[lane] = make_float4(e0, e1, e2, __int_as_float(s));
        int cnt = end - base; if (cnt > 64) cnt = 64;
#pragma unroll 2
        for (int t = 0; t < cnt; t += 2) {
            float4 ed = exw[t + half];           // zero-filled beyond cnt -> safe
            int ss = __float_as_int(ed.w);
            float4 hv = *(const float4*)(Hm + ((size_t)ss << 7) + c0);
            float h128 = Hl[ss];
            float w0 = (c0     < 43) ? ed.x : ((c0     < 86) ? ed.y : ed.z);
            float w1 = (c0 + 1 < 43) ? ed.x : ((c0 + 1 < 86) ? ed.y : ed.z);
            float w2 = (c0 + 2 < 43) ? ed.x : ((c0 + 2 < 86) ? ed.y : ed.z);
            float w3 = (c0 + 3 < 43) ? ed.x : ((c0 + 3 < 86) ? ed.y : ed.z);
            acc.x += w0 * hv.x; acc.y += w1 * hv.y;
            acc.z += w2 * hv.z; acc.w += w3 * hv.w;
            acc128 += ed.z * h128;
        }
    }
    acc.x += __shfl_xor(acc.x, 32, 64);
    acc.y += __shfl_xor(acc.y, 32, 64);
    acc.z += __shfl_xor(acc.z, 32, 64);
    acc.w += __shfl_xor(acc.w, 32, 64);
    acc128 += __shfl_xor(acc128, 32, 64);
#pragma unroll
    for (int off = 32; off; off >>= 1) {
        s0 += __shfl_xor(s0, off, 64);
        s1 += __shfl_xor(s1, off, 64);
        s2 += __shfl_xor(s2, off, 64);
    }
    float d0 = 1.f / (s0 + 1e-16f);
    float d1 = 1.f / (s1 + 1e-16f);
    float d2 = 1.f / (s2 + 1e-16f);
    if (half == 0) {
        float4 bv = *(const float4*)(bias + c0);
        float o0 = acc.x * ((c0     < 43) ? d0 : ((c0     < 86) ? d1 : d2)) + bv.x;
        float o1 = acc.y * ((c0 + 1 < 43) ? d0 : ((c0 + 1 < 86) ? d1 : d2)) + bv.y;
        float o2 = acc.z * ((c0 + 2 < 43) ? d0 : ((c0 + 2 < 86) ? d1 : d2)) + bv.z;
        float o3 = acc.w * ((c0 + 3 < 43) ? d0 : ((c0 + 3 < 86) ? d1 : d2)) + bv.w;
        if (ACT) { o0 = lrelu(o0); o1 = lrelu(o1); o2 = lrelu(o2); o3 = lrelu(o3); }
        *(float4*)(Om + ((size_t)wid << 7) + c0) = make_float4(o0, o1, o2, o3);
        if (lane == 0) {
            float o128 = acc128 * d2 + bias[128];
            if (ACT) o128 = lrelu(o128);
            Ol[wid] = o128;
        }
    }
}

// ---------------- layer 2: fused GEMM (129->6) + logits, wave per node ----------------
__global__ void layer2_node_kernel(const float* __restrict__ Om, const float* __restrict__ Ol,
                                   const float* __restrict__ W2, const float* __restrict__ a2s,
                                   const float* __restrict__ a2d, float* __restrict__ H2,
                                   float* __restrict__ al2, float* __restrict__ ar2) {
    int lane = threadIdx.x & 63;
    int wid  = blockIdx.x * 4 + (threadIdx.x >> 6);
    if (wid >= N_NODES) return;
    int c0 = 2 * lane;
    float2 xv  = *(const float2*)(Om + ((size_t)wid << 7) + c0);
    float x128 = Ol[wid];
    const float* w0p = W2 + c0 * OUTC;
    const float* w1p = W2 + (c0 + 1) * OUTC;
    float m = (lane == 0) ? x128 : 0.f;
    float p[OUTC];
#pragma unroll
    for (int c = 0; c < OUTC; ++c)
        p[c] = xv.x * w0p[c] + xv.y * w1p[c] + m * W2[128 * OUTC + c];
#pragma unroll
    for (int off = 32; off; off >>= 1)
#pragma unroll
        for (int c = 0; c < OUTC; ++c) p[c] += __shfl_xor(p[c], off, 64);
    float sl = 0.f, sr = 0.f;
#pragma unroll
    for (int c = 0; c < OUTC; ++c) { sl += p[c] * a2s[c]; sr += p[c] * a2d[c]; }
    if (lane == 0) {
#pragma unroll
        for (int c = 0; c < OUTC; ++c) H2[wid * OUTC + c] = p[c];
        al2[wid] = sl;
        ar2[wid] = sr;
    }
}

// ---------------- layer 2 aggregate (1 head, 6 ch), 8 edges/iter ----------------
__global__ void agg6_kernel(const float* __restrict__ H2, const float* __restrict__ al2,
                            const float* __restrict__ ar2, const int* __restrict__ rowp,
                            const int* __restrict__ srcs, const float* __restrict__ b2,
                            float* __restrict__ out) {
    __shared__ float2 exs[4][64];
    int lane = threadIdx.x & 63;
    int wv   = threadIdx.x >> 6;
    int wid  = blockIdx.x * 4 + wv;
    if (wid >= N_NODES) return;
    int beg = rowp[wid], end = rowp[wid + 1];
    float ard = ar2[wid];
    int grp = lane >> 3;            // edge within the 8-pack
    int myc = lane & 7;
    int cc  = (myc < OUTC) ? myc : 0;
    float ssum = 0.f, acc = 0.f;
    float2* exw = exs[wv];
    for (int base = beg; base < end; base += 64) {
        int i = base + lane;
        float ex = 0.f;
        int s = 0;
        if (i < end) {
            s = srcs[i];
            ex = __expf(lrelu(al2[s] + ard));
            ssum += ex;
        }
        exw[lane] = make_float2(ex, __int_as_float(s));
        int cnt = end - base; if (cnt > 64) cnt = 64;
        for (int t = 0; t < cnt; t += 8) {
            float2 ed = exw[t + grp];            // zero-filled beyond cnt -> safe
            int ss = __float_as_int(ed.y);
            acc += ed.x * H2[ss * OUTC + cc];
        }
    }
    acc += __shfl_xor(acc, 8, 64);
    acc += __shfl_xor(acc, 16, 64);
    acc += __shfl_xor(acc, 32, 64);
#pragma unroll
    for (int off = 32; off; off >>= 1) ssum += __shfl_xor(ssum, off, 64);
    float dinv = 1.f / (ssum + 1e-16f);
    if (lane < OUTC) out[(size_t)wid * OUTC + lane] = acc * dinv + b2[lane];
}

// ---------------- launch ----------------

extern "C" void kernel_launch(void* const* d_in, const int* in_sizes, int n_in,
                              void* d_out, int out_size, void* d_ws, size_t ws_size,
                              hipStream_t stream) {
    const float* x   = (const float*)d_in[0];
    const int*   ei  = (const int*)d_in[1];
    const float* W0  = (const float*)d_in[2];
    const float* a0s = (const float*)d_in[3];
    const float* a0d = (const float*)d_in[4];
    const float* b0  = (const float*)d_in[5];
    const float* W1  = (const float*)d_in[6];
    const float* a1s = (const float*)d_in[7];
    const float* a1d = (const float*)d_in[8];
    const float* b1  = (const float*)d_in[9];
    const float* W2  = (const float*)d_in[10];
    const float* a2s = (const float*)d_in[11];
    const float* a2d = (const float*)d_in[12];
    const float* b2  = (const float*)d_in[13];
    float* out = (float*)d_out;

    char* p = (char*)d_ws;
    auto take = [&](size_t bytes) -> void* {
        void* r = (void*)p;
        p += (bytes + 255) & ~(size_t)255;
        return r;
    };
    int*   cnt     = (int*)take((size_t)N_NODES * 4);
    int*   rowp    = (int*)take((size_t)(N_NODES + 1) * 4);
    int*   cursor  = (int*)take((size_t)N_NODES * 4);
    int*   csr_src = (int*)take((size_t)ET * 4);
    float* al      = (float*)take((size_t)N_NODES * 3 * 4);
    float* ar      = (float*)take((size_t)N_NODES * 3 * 4);
    float* Hm      = (float*)take((size_t)N_NODES * 128 * 4);
    float* Hl      = (float*)take((size_t)N_NODES * 4);
    float* Om      = (float*)take((size_t)N_NODES * 128 * 4);
    float* Ol      = (float*)take((size_t)N_NODES * 4);
    float* Wp0     = (float*)take((size_t)128 * 132 * 4);
    float* Wp1     = (float*)take((size_t)129 * 132 * 4);
    float* wcol0   = (float*)take((size_t)128 * 4);
    float* wcol1   = (float*)take((size_t)129 * 4);

    const int* esrc = ei;
    const int* edst = ei + N_EDGES;

    hipMemsetAsync(cnt, 0, (size_t)N_NODES * 4, stream);
    count_kernel<<<(ET + 255) / 256, 256, 0, stream>>>(edst, cnt);
    scan_kernel<<<1, 1024, 0, stream>>>(cnt, rowp, cursor);
    scatter_kernel<<<(ET + 255) / 256, 256, 0, stream>>>(esrc, edst, cursor, csr_src);

    padw_kernel<<<(128 * 132 + 255) / 256, 256, 0, stream>>>(W0, Wp0, wcol0, 128);
    padw_kernel<<<(129 * 132 + 255) / 256, 256, 0, stream>>>(W1, Wp1, wcol1, 129);

    const int gemm_grid = (N_NODES + 31) / 32;
    const int node_grid = (N_NODES + 3) / 4;

    // layer 0
    gemm_kernel<128><<<gemm_grid, 256, 0, stream>>>(x, x, Wp0, wcol0, Hm, Hl);
    alar_kernel<<<node_grid, 256, 0, stream>>>(Hm, Hl, a0s, a0d, al, ar);
    agg129_kernel<true><<<node_grid, 256, 0, stream>>>(Hm, Hl, al, ar, rowp, csr_src, b0, Om, Ol);

    // layer 1
    gemm_kernel<129><<<gemm_grid, 256, 0, stream>>>(Om, Ol, Wp1, wcol1, Hm, Hl);
    alar_kernel<<<node_grid, 256, 0, stream>>>(Hm, Hl, a1s, a1d, al, ar);
    agg129_kernel<true><<<node_grid, 256, 0, stream>>>(Hm, Hl, al, ar, rowp, csr_src, b1, Om, Ol);

    // layer 2
    layer2_node_kernel<<<node_grid, 256, 0, stream>>>(Om, Ol, W2, a2s, a2d, Hm, al, ar);
    agg6_kernel<<<node_grid, 256, 0, stream>>>(Hm, al, ar, rowp, csr_src, b2, out);
}

// Round 4
// 443.812 us; speedup vs baseline: 1.5976x; 1.1191x over previous
//
#include <hip/hip_runtime.h>

#define N_NODES 50000
#define N_EDGES 800000
#define ET (N_EDGES + N_NODES)   // edges + self loops = 850000
#define MID 129
#define OUTC 6

typedef _Float16 half2v __attribute__((ext_vector_type(2)));
typedef _Float16 half8  __attribute__((ext_vector_type(8)));

__device__ __forceinline__ float lrelu(float x) { return x > 0.f ? x : 0.2f * x; }

// ---------------- CSR build ----------------

__global__ void count_kernel(const int* __restrict__ dst, int* __restrict__ cnt) {
    int e0 = (blockIdx.x * blockDim.x + threadIdx.x) * 8;
    if (e0 >= ET) return;
    if (e0 + 8 <= N_EDGES) {
        int4 a = *(const int4*)(dst + e0);
        int4 b = *(const int4*)(dst + e0 + 4);
        atomicAdd(&cnt[a.x], 1); atomicAdd(&cnt[a.y], 1);
        atomicAdd(&cnt[a.z], 1); atomicAdd(&cnt[a.w], 1);
        atomicAdd(&cnt[b.x], 1); atomicAdd(&cnt[b.y], 1);
        atomicAdd(&cnt[b.z], 1); atomicAdd(&cnt[b.w], 1);
    } else {
#pragma unroll
        for (int j = 0; j < 8; ++j) {
            int e = e0 + j;
            if (e < ET) {
                int d = (e < N_EDGES) ? dst[e] : (e - N_EDGES);
                atomicAdd(&cnt[d], 1);
            }
        }
    }
}

// single-block exclusive scan, 4 elements/thread (13 tiles of 4096)
__global__ void scan_kernel(const int* __restrict__ cnt, int* __restrict__ row,
                            int* __restrict__ cursor) {
    __shared__ int wsum[16];
    __shared__ int carry_s;
    int tid  = threadIdx.x;
    int lane = tid & 63;
    int wv   = tid >> 6;
    if (tid == 0) carry_s = 0;
    __syncthreads();
    for (int base = 0; base < N_NODES; base += 4096) {
        int i0 = base + tid * 4;
        int v0 = 0, v1 = 0, v2 = 0, v3 = 0;
        if (i0 + 3 < N_NODES) {
            const int4 q = *(const int4*)(cnt + i0);
            v0 = q.x; v1 = q.y; v2 = q.z; v3 = q.w;
        } else {
            if (i0     < N_NODES) v0 = cnt[i0];
            if (i0 + 1 < N_NODES) v1 = cnt[i0 + 1];
            if (i0 + 2 < N_NODES) v2 = cnt[i0 + 2];
            if (i0 + 3 < N_NODES) v3 = cnt[i0 + 3];
        }
        int t = v0 + v1 + v2 + v3;
        int x = t;
#pragma unroll
        for (int off = 1; off < 64; off <<= 1) {
            int sh = __shfl_up(x, off, 64);
            if (lane >= off) x += sh;
        }
        if (lane == 63) wsum[wv] = x;
        __syncthreads();
        if (wv == 0) {
            int w = (lane < 16) ? wsum[lane] : 0;
#pragma unroll
            for (int off = 1; off < 16; off <<= 1) {
                int sh = __shfl_up(w, off, 64);
                if (lane >= off) w += sh;
            }
            if (lane < 16) wsum[lane] = w;
        }
        __syncthreads();
        int wexcl = wv ? wsum[wv - 1] : 0;
        int total = wsum[15];
        int c0    = carry_s;
        __syncthreads();
        int e = c0 + wexcl + (x - t);
        if (i0     < N_NODES) { row[i0]     = e; cursor[i0]     = e; } e += v0;
        if (i0 + 1 < N_NODES) { row[i0 + 1] = e; cursor[i0 + 1] = e; } e += v1;
        if (i0 + 2 < N_NODES) { row[i0 + 2] = e; cursor[i0 + 2] = e; } e += v2;
        if (i0 + 3 < N_NODES) { row[i0 + 3] = e; cursor[i0 + 3] = e; }
        if (tid == 0) carry_s = c0 + total;
        __syncthreads();
    }
    if (tid == 0) row[N_NODES] = carry_s;
}

__global__ void scatter_kernel(const int* __restrict__ src, const int* __restrict__ dst,
                               int* __restrict__ cursor, int* __restrict__ csr_src) {
    int e0 = (blockIdx.x * blockDim.x + threadIdx.x) * 8;
    if (e0 >= ET) return;
    int ss[8], dd[8];
    int nv = 8;
    if (e0 + 8 <= N_EDGES) {
        int4 a = *(const int4*)(src + e0);
        int4 b = *(const int4*)(src + e0 + 4);
        ss[0] = a.x; ss[1] = a.y; ss[2] = a.z; ss[3] = a.w;
        ss[4] = b.x; ss[5] = b.y; ss[6] = b.z; ss[7] = b.w;
        int4 c = *(const int4*)(dst + e0);
        int4 d = *(const int4*)(dst + e0 + 4);
        dd[0] = c.x; dd[1] = c.y; dd[2] = c.z; dd[3] = c.w;
        dd[4] = d.x; dd[5] = d.y; dd[6] = d.z; dd[7] = d.w;
    } else {
        nv = 0;
#pragma unroll
        for (int j = 0; j < 8; ++j) {
            int e = e0 + j;
            if (e < ET) {
                if (e < N_EDGES) { ss[j] = src[e]; dd[j] = dst[e]; }
                else             { ss[j] = dd[j] = e - N_EDGES; }
                nv = j + 1;
            }
        }
    }
#pragma unroll
    for (int j = 0; j < 8; ++j) {
        if (j < nv) {
            int p = atomicAdd(&cursor[dd[j]], 1);
            csr_src[p] = ss[j];
        }
    }
}

// ---- W pre-pad (both layers): [K][129] -> [K][132] + col-128 extract ----
__global__ void padw2_kernel(const float* __restrict__ W0, const float* __restrict__ W1,
                             float* __restrict__ Wp0, float* __restrict__ Wp1,
                             float* __restrict__ wcol0, float* __restrict__ wcol1) {
    int i = blockIdx.x * blockDim.x + threadIdx.x;
    const int TOT0 = 128 * 132;
    const int TOT1 = 129 * 132;
    if (i < TOT0) {
        int k = i / 132, c = i - k * 132;
        float v = (c < MID) ? W0[k * MID + c] : 0.f;
        Wp0[i] = v;
        if (c == 128) wcol0[k] = v;
    } else if (i < TOT0 + TOT1) {
        int ii = i - TOT0;
        int k = ii / 132, c = ii - k * 132;
        float v = (c < MID) ? W1[k * MID + c] : 0.f;
        Wp1[ii] = v;
        if (c == 128) wcol1[k] = v;
    }
}

// ---------------- GEMM (fp32 vector ALU, fp16 output) ----------------
// block = 256 = 4 waves; 8 rows/wave; lane owns output cols {2l, 2l+1}; col 128 via butterfly
template <int K>
__global__ void gemm_kernel(const float* __restrict__ X, const float* __restrict__ Xl,
                            const float* __restrict__ Wp, const float* __restrict__ wcol,
                            _Float16* __restrict__ Hm16, float* __restrict__ Hl) {
    __shared__ float xs[32 * 132];
    __shared__ float Wc[132];
    int tid  = threadIdx.x;
    int row0 = blockIdx.x * 32;
    {
        int k = tid & 127;
        for (int rr = tid >> 7; rr < 32; rr += 2) {
            int row = row0 + rr;
            xs[rr * 132 + k] = (row < N_NODES) ? X[((size_t)row << 7) + k] : 0.f;
            if (k == 0)
                xs[rr * 132 + 128] = (K == 129 && row < N_NODES) ? Xl[row] : 0.f;
        }
        if (tid < K) Wc[tid] = wcol[tid];
    }
    __syncthreads();

    int wave = tid >> 6, lane = tid & 63;
    int c0 = 2 * lane;
    const float* xbase = xs + wave * 8 * 132;
    float2 acc[8];
#pragma unroll
    for (int r = 0; r < 8; ++r) acc[r] = make_float2(0.f, 0.f);

    for (int k0 = 0; k0 < 128; k0 += 4) {
        float2 wv[4];
#pragma unroll
        for (int j = 0; j < 4; ++j)
            wv[j] = *(const float2*)(Wp + (k0 + j) * 132 + c0);
#pragma unroll
        for (int r = 0; r < 8; ++r) {
            float4 xq = *(const float4*)(xbase + r * 132 + k0);
            acc[r].x += xq.x * wv[0].x; acc[r].y += xq.x * wv[0].y;
            acc[r].x += xq.y * wv[1].x; acc[r].y += xq.y * wv[1].y;
            acc[r].x += xq.z * wv[2].x; acc[r].y += xq.z * wv[2].y;
            acc[r].x += xq.w * wv[3].x; acc[r].y += xq.w * wv[3].y;
        }
    }
    if (K == 129) {
        float2 wv = *(const float2*)(Wp + 128 * 132 + c0);
#pragma unroll
        for (int r = 0; r < 8; ++r) {
            float xv = xbase[r * 132 + 128];
            acc[r].x += xv * wv.x; acc[r].y += xv * wv.y;
        }
    }
#pragma unroll
    for (int r = 0; r < 8; ++r) {
        int row = row0 + wave * 8 + r;
        if (row < N_NODES) {
            half2v hv;
            hv[0] = (_Float16)acc[r].x;
            hv[1] = (_Float16)acc[r].y;
            *(half2v*)(Hm16 + ((size_t)row << 7) + c0) = hv;
        }
    }
    // col 128: lanes split k, butterfly-sum per row
#pragma unroll
    for (int r = 0; r < 8; ++r) {
        const float* xr = xbase + r * 132;
        float p = xr[lane] * Wc[lane] + xr[64 + lane] * Wc[64 + lane];
        if (K == 129 && lane == 0) p += xr[128] * Wc[128];
#pragma unroll
        for (int off = 32; off; off >>= 1) p += __shfl_xor(p, off, 64);
        int row = row0 + wave * 8 + r;
        if (lane == 0 && row < N_NODES) Hl[row] = p;
    }
}

// ---------------- attention logits: wave per node, fp16 h ----------------
__global__ void alar_kernel(const _Float16* __restrict__ Hm16, const float* __restrict__ Hl,
                            const float* __restrict__ asf, const float* __restrict__ adf,
                            float* __restrict__ al, float* __restrict__ ar) {
    int lane = threadIdx.x & 63;
    int wid  = blockIdx.x * 4 + (threadIdx.x >> 6);
    if (wid >= N_NODES) return;
    int c0 = 2 * lane, c1 = c0 + 1;
    int h0 = c0 / 43, h1 = c1 / 43;
    float as0 = asf[c0], as1 = asf[c1], ad0 = adf[c0], ad1 = adf[c1];
    float as128 = asf[128], ad128 = adf[128];

    half2v hv = *(const half2v*)(Hm16 + ((size_t)wid << 7) + c0);
    float hx = (float)hv[0], hy = (float)hv[1];
    float h128 = Hl[wid];

    float plx = hx * as0, ply = hy * as1;
    float prx = hx * ad0, pry = hy * ad1;
    float pl[3], pr[3];
#pragma unroll
    for (int h = 0; h < 3; ++h) {
        pl[h] = (h0 == h ? plx : 0.f) + (h1 == h ? ply : 0.f);
        pr[h] = (h0 == h ? prx : 0.f) + (h1 == h ? pry : 0.f);
    }
    float m0 = (lane == 0) ? 1.f : 0.f;
    pl[2] += m0 * h128 * as128;
    pr[2] += m0 * h128 * ad128;
#pragma unroll
    for (int off = 32; off; off >>= 1) {
#pragma unroll
        for (int h = 0; h < 3; ++h) {
            pl[h] += __shfl_xor(pl[h], off, 64);
            pr[h] += __shfl_xor(pr[h], off, 64);
        }
    }
    if (lane == 0) {
#pragma unroll
        for (int h = 0; h < 3; ++h) {
            al[wid * 3 + h] = pl[h];
            ar[wid * 3 + h] = pr[h];
        }
    }
}

// ------- fused softmax + aggregation (129 ch, 3 heads), 4 edges/iter, fp16 gathers -------
template <bool ACT>
__global__ void agg129_kernel(const _Float16* __restrict__ Hm16, const float* __restrict__ Hl,
                              const float* __restrict__ al, const float* __restrict__ ar,
                              const int* __restrict__ rowp, const int* __restrict__ srcs,
                              const float* __restrict__ bias, float* __restrict__ Om,
                              float* __restrict__ Ol) {
    __shared__ float4 exs[4][64];
    int lane = threadIdx.x & 63;
    int wv   = threadIdx.x >> 6;
    int wid  = blockIdx.x * 4 + wv;
    if (wid >= N_NODES) return;

    int beg = rowp[wid], end = rowp[wid + 1];
    float ard0 = ar[wid * 3], ard1 = ar[wid * 3 + 1], ard2 = ar[wid * 3 + 2];

    int g  = lane >> 4;        // edge within quad
    int q  = lane & 15;        // channel group: channels 8q..8q+7
    int cb = 8 * q;

    bool bm0[8], bm1[8];
#pragma unroll
    for (int j = 0; j < 8; ++j) {
        bm0[j] = (cb + j) < 43;
        bm1[j] = (cb + j) < 86;
    }

    float accv[8];
#pragma unroll
    for (int j = 0; j < 8; ++j) accv[j] = 0.f;
    float acc128 = 0.f;
    float s0 = 0.f, s1 = 0.f, s2 = 0.f;
    float4* exw = exs[wv];

    for (int base = beg; base < end; base += 64) {
        int i = base + lane;
        float e0 = 0.f, e1 = 0.f, e2 = 0.f;
        int s = 0;
        if (i < end) {
            s = srcs[i];
            const float* ap = al + s * 3;
            e0 = __expf(lrelu(ap[0] + ard0));
            e1 = __expf(lrelu(ap[1] + ard1));
            e2 = __expf(lrelu(ap[2] + ard2));
            s0 += e0; s1 += e1; s2 += e2;
        }
        exw[lane] = make_float4(e0, e1, e2, __int_as_float(s));
        int cnt = end - base; if (cnt > 64) cnt = 64;
        for (int t = 0; t < cnt; t += 4) {
            float4 ed = exw[t + g];              // zero-filled beyond cnt -> safe
            int ss = __float_as_int(ed.w);
            half8 hv = *(const half8*)(Hm16 + ((size_t)ss << 7) + cb);
            if (q == 0) acc128 += ed.z * Hl[ss];
#pragma unroll
            for (int j = 0; j < 8; ++j) {
                float w = bm0[j] ? ed.x : (bm1[j] ? ed.y : ed.z);
                accv[j] += w * (float)hv[j];
            }
        }
    }
#pragma unroll
    for (int off = 16; off <= 32; off <<= 1) {
#pragma unroll
        for (int j = 0; j < 8; ++j) accv[j] += __shfl_xor(accv[j], off, 64);
        acc128 += __shfl_xor(acc128, off, 64);
    }
#pragma unroll
    for (int off = 32; off; off >>= 1) {
        s0 += __shfl_xor(s0, off, 64);
        s1 += __shfl_xor(s1, off, 64);
        s2 += __shfl_xor(s2, off, 64);
    }
    float d0 = 1.f / (s0 + 1e-16f);
    float d1 = 1.f / (s1 + 1e-16f);
    float d2 = 1.f / (s2 + 1e-16f);
    if (g == 0) {
        float o[8];
        float4 bv0 = *(const float4*)(bias + cb);
        float4 bv1 = *(const float4*)(bias + cb + 4);
        float bb[8] = {bv0.x, bv0.y, bv0.z, bv0.w, bv1.x, bv1.y, bv1.z, bv1.w};
#pragma unroll
        for (int j = 0; j < 8; ++j) {
            float dv = bm0[j] ? d0 : (bm1[j] ? d1 : d2);
            o[j] = accv[j] * dv + bb[j];
            if (ACT) o[j] = lrelu(o[j]);
        }
        *(float4*)(Om + ((size_t)wid << 7) + cb)     = make_float4(o[0], o[1], o[2], o[3]);
        *(float4*)(Om + ((size_t)wid << 7) + cb + 4) = make_float4(o[4], o[5], o[6], o[7]);
        if (lane == 0) {
            float o128 = acc128 * d2 + bias[128];
            if (ACT) o128 = lrelu(o128);
            Ol[wid] = o128;
        }
    }
}

// ---------------- layer 2: fused GEMM (129->6) + logits, wave per node ----------------
__global__ void layer2_node_kernel(const float* __restrict__ Om, const float* __restrict__ Ol,
                                   const float* __restrict__ W2, const float* __restrict__ a2s,
                                   const float* __restrict__ a2d, float* __restrict__ H2,
                                   float* __restrict__ al2, float* __restrict__ ar2) {
    int lane = threadIdx.x & 63;
    int wid  = blockIdx.x * 4 + (threadIdx.x >> 6);
    if (wid >= N_NODES) return;
    int c0 = 2 * lane;
    float2 xv  = *(const float2*)(Om + ((size_t)wid << 7) + c0);
    float x128 = Ol[wid];
    const float* w0p = W2 + c0 * OUTC;
    const float* w1p = W2 + (c0 + 1) * OUTC;
    float m = (lane == 0) ? x128 : 0.f;
    float p[OUTC];
#pragma unroll
    for (int c = 0; c < OUTC; ++c)
        p[c] = xv.x * w0p[c] + xv.y * w1p[c] + m * W2[128 * OUTC + c];
#pragma unroll
    for (int off = 32; off; off >>= 1)
#pragma unroll
        for (int c = 0; c < OUTC; ++c) p[c] += __shfl_xor(p[c], off, 64);
    float sl = 0.f, sr = 0.f;
#pragma unroll
    for (int c = 0; c < OUTC; ++c) { sl += p[c] * a2s[c]; sr += p[c] * a2d[c]; }
    if (lane == 0) {
#pragma unroll
        for (int c = 0; c < OUTC; ++c) H2[wid * OUTC + c] = p[c];
        al2[wid] = sl;
        ar2[wid] = sr;
    }
}

// ---------------- layer 2 aggregate (1 head, 6 ch), 8 edges/iter ----------------
__global__ void agg6_kernel(const float* __restrict__ H2, const float* __restrict__ al2,
                            const float* __restrict__ ar2, const int* __restrict__ rowp,
                            const int* __restrict__ srcs, const float* __restrict__ b2,
                            float* __restrict__ out) {
    __shared__ float2 exs[4][64];
    int lane = threadIdx.x & 63;
    int wv   = threadIdx.x >> 6;
    int wid  = blockIdx.x * 4 + wv;
    if (wid >= N_NODES) return;
    int beg = rowp[wid], end = rowp[wid + 1];
    float ard = ar2[wid];
    int grp = lane >> 3;
    int myc = lane & 7;
    int cc  = (myc < OUTC) ? myc : 0;
    float ssum = 0.f, acc = 0.f;
    float2* exw = exs[wv];
    for (int base = beg; base < end; base += 64) {
        int i = base + lane;
        float ex = 0.f;
        int s = 0;
        if (i < end) {
            s = srcs[i];
            ex = __expf(lrelu(al2[s] + ard));
            ssum += ex;
        }
        exw[lane] = make_float2(ex, __int_as_float(s));
        int cnt = end - base; if (cnt > 64) cnt = 64;
        for (int t = 0; t < cnt; t += 8) {
            float2 ed = exw[t + grp];
            int ss = __float_as_int(ed.y);
            acc += ed.x * H2[ss * OUTC + cc];
        }
    }
    acc += __shfl_xor(acc, 8, 64);
    acc += __shfl_xor(acc, 16, 64);
    acc += __shfl_xor(acc, 32, 64);
#pragma unroll
    for (int off = 32; off; off >>= 1) ssum += __shfl_xor(ssum, off, 64);
    float dinv = 1.f / (ssum + 1e-16f);
    if (lane < OUTC) out[(size_t)wid * OUTC + lane] = acc * dinv + b2[lane];
}

// ---------------- launch ----------------

extern "C" void kernel_launch(void* const* d_in, const int* in_sizes, int n_in,
                              void* d_out, int out_size, void* d_ws, size_t ws_size,
                              hipStream_t stream) {
    const float* x   = (const float*)d_in[0];
    const int*   ei  = (const int*)d_in[1];
    const float* W0  = (const float*)d_in[2];
    const float* a0s = (const float*)d_in[3];
    const float* a0d = (const float*)d_in[4];
    const float* b0  = (const float*)d_in[5];
    const float* W1  = (const float*)d_in[6];
    const float* a1s = (const float*)d_in[7];
    const float* a1d = (const float*)d_in[8];
    const float* b1  = (const float*)d_in[9];
    const float* W2  = (const float*)d_in[10];
    const float* a2s = (const float*)d_in[11];
    const float* a2d = (const float*)d_in[12];
    const float* b2  = (const float*)d_in[13];
    float* out = (float*)d_out;

    char* p = (char*)d_ws;
    auto take = [&](size_t bytes) -> void* {
        void* r = (void*)p;
        p += (bytes + 255) & ~(size_t)255;
        return r;
    };
    int*      cnt     = (int*)take((size_t)N_NODES * 4);
    int*      rowp    = (int*)take((size_t)(N_NODES + 1) * 4);
    int*      cursor  = (int*)take((size_t)N_NODES * 4);
    int*      csr_src = (int*)take((size_t)ET * 4);
    float*    al      = (float*)take((size_t)N_NODES * 3 * 4);
    float*    ar      = (float*)take((size_t)N_NODES * 3 * 4);
    _Float16* Hm16    = (_Float16*)take((size_t)N_NODES * 128 * 2);
    float*    Hl      = (float*)take((size_t)N_NODES * 4);
    float*    Om      = (float*)take((size_t)N_NODES * 128 * 4);
    float*    Ol      = (float*)take((size_t)N_NODES * 4);
    float*    Wp0     = (float*)take((size_t)128 * 132 * 4);
    float*    Wp1     = (float*)take((size_t)129 * 132 * 4);
    float*    wcol0   = (float*)take((size_t)128 * 4);
    float*    wcol1   = (float*)take((size_t)129 * 4);
    float*    H2      = (float*)take((size_t)N_NODES * OUTC * 4);

    const int* esrc = ei;
    const int* edst = ei + N_EDGES;

    hipMemsetAsync(cnt, 0, (size_t)N_NODES * 4, stream);
    const int epk_grid = ((ET + 7) / 8 + 255) / 256;
    count_kernel<<<epk_grid, 256, 0, stream>>>(edst, cnt);
    scan_kernel<<<1, 1024, 0, stream>>>(cnt, rowp, cursor);
    scatter_kernel<<<epk_grid, 256, 0, stream>>>(esrc, edst, cursor, csr_src);

    padw2_kernel<<<((128 + 129) * 132 + 255) / 256, 256, 0, stream>>>(W0, W1, Wp0, Wp1, wcol0, wcol1);

    const int gemm_grid = (N_NODES + 31) / 32;
    const int node_grid = (N_NODES + 3) / 4;

    // layer 0
    gemm_kernel<128><<<gemm_grid, 256, 0, stream>>>(x, x, Wp0, wcol0, Hm16, Hl);
    alar_kernel<<<node_grid, 256, 0, stream>>>(Hm16, Hl, a0s, a0d, al, ar);
    agg129_kernel<true><<<node_grid, 256, 0, stream>>>(Hm16, Hl, al, ar, rowp, csr_src, b0, Om, Ol);

    // layer 1
    gemm_kernel<129><<<gemm_grid, 256, 0, stream>>>(Om, Ol, Wp1, wcol1, Hm16, Hl);
    alar_kernel<<<node_grid, 256, 0, stream>>>(Hm16, Hl, a1s, a1d, al, ar);
    agg129_kernel<true><<<node_grid, 256, 0, stream>>>(Hm16, Hl, al, ar, rowp, csr_src, b1, Om, Ol);

    // layer 2
    layer2_node_kernel<<<node_grid, 256, 0, stream>>>(Om, Ol, W2, a2s, a2d, H2, al, ar);
    agg6_kernel<<<node_grid, 256, 0, stream>>>(H2, al, ar, rowp, csr_src, b2, out);
}

// Round 5
// 438.741 us; speedup vs baseline: 1.6160x; 1.0116x over previous
//
#include <hip/hip_runtime.h>

#define N_NODES 50000
#define N_EDGES 800000
#define ET (N_EDGES + N_NODES)   // edges + self loops = 850000
#define MID 129
#define OUTC 6

typedef _Float16 half2v __attribute__((ext_vector_type(2)));
typedef _Float16 half8  __attribute__((ext_vector_type(8)));

__device__ __forceinline__ float lrelu(float x) { return x > 0.f ? x : 0.2f * x; }

// ---------------- CSR build ----------------

__global__ void count_kernel(const int* __restrict__ dst, int* __restrict__ cnt) {
    int e0 = (blockIdx.x * blockDim.x + threadIdx.x) * 2;
    if (e0 >= ET) return;
    if (e0 + 2 <= N_EDGES) {
        int2 a = *(const int2*)(dst + e0);
        atomicAdd(&cnt[a.x], 1);
        atomicAdd(&cnt[a.y], 1);
    } else {
#pragma unroll
        for (int j = 0; j < 2; ++j) {
            int e = e0 + j;
            if (e < ET) {
                int d = (e < N_EDGES) ? dst[e] : (e - N_EDGES);
                atomicAdd(&cnt[d], 1);
            }
        }
    }
}

// single-block exclusive scan, 4 elements/thread (13 tiles of 4096)
__global__ void scan_kernel(const int* __restrict__ cnt, int* __restrict__ row,
                            int* __restrict__ cursor) {
    __shared__ int wsum[16];
    __shared__ int carry_s;
    int tid  = threadIdx.x;
    int lane = tid & 63;
    int wv   = tid >> 6;
    if (tid == 0) carry_s = 0;
    __syncthreads();
    for (int base = 0; base < N_NODES; base += 4096) {
        int i0 = base + tid * 4;
        int v0 = 0, v1 = 0, v2 = 0, v3 = 0;
        if (i0 + 3 < N_NODES) {
            const int4 q = *(const int4*)(cnt + i0);
            v0 = q.x; v1 = q.y; v2 = q.z; v3 = q.w;
        } else {
            if (i0     < N_NODES) v0 = cnt[i0];
            if (i0 + 1 < N_NODES) v1 = cnt[i0 + 1];
            if (i0 + 2 < N_NODES) v2 = cnt[i0 + 2];
            if (i0 + 3 < N_NODES) v3 = cnt[i0 + 3];
        }
        int t = v0 + v1 + v2 + v3;
        int x = t;
#pragma unroll
        for (int off = 1; off < 64; off <<= 1) {
            int sh = __shfl_up(x, off, 64);
            if (lane >= off) x += sh;
        }
        if (lane == 63) wsum[wv] = x;
        __syncthreads();
        if (wv == 0) {
            int w = (lane < 16) ? wsum[lane] : 0;
#pragma unroll
            for (int off = 1; off < 16; off <<= 1) {
                int sh = __shfl_up(w, off, 64);
                if (lane >= off) w += sh;
            }
            if (lane < 16) wsum[lane] = w;
        }
        __syncthreads();
        int wexcl = wv ? wsum[wv - 1] : 0;
        int total = wsum[15];
        int c0    = carry_s;
        __syncthreads();
        int e = c0 + wexcl + (x - t);
        if (i0     < N_NODES) { row[i0]     = e; cursor[i0]     = e; } e += v0;
        if (i0 + 1 < N_NODES) { row[i0 + 1] = e; cursor[i0 + 1] = e; } e += v1;
        if (i0 + 2 < N_NODES) { row[i0 + 2] = e; cursor[i0 + 2] = e; } e += v2;
        if (i0 + 3 < N_NODES) { row[i0 + 3] = e; cursor[i0 + 3] = e; }
        if (tid == 0) carry_s = c0 + total;
        __syncthreads();
    }
    if (tid == 0) row[N_NODES] = carry_s;
}

__global__ void scatter_kernel(const int* __restrict__ src, const int* __restrict__ dst,
                               int* __restrict__ cursor, unsigned short* __restrict__ csr_src) {
    int e0 = (blockIdx.x * blockDim.x + threadIdx.x) * 4;
    if (e0 >= ET) return;
    int ss[4], dd[4];
    int nv = 4;
    if (e0 + 4 <= N_EDGES) {
        int4 a = *(const int4*)(src + e0);
        ss[0] = a.x; ss[1] = a.y; ss[2] = a.z; ss[3] = a.w;
        int4 c = *(const int4*)(dst + e0);
        dd[0] = c.x; dd[1] = c.y; dd[2] = c.z; dd[3] = c.w;
    } else {
        nv = 0;
#pragma unroll
        for (int j = 0; j < 4; ++j) {
            int e = e0 + j;
            if (e < ET) {
                if (e < N_EDGES) { ss[j] = src[e]; dd[j] = dst[e]; }
                else             { ss[j] = dd[j] = e - N_EDGES; }
                nv = j + 1;
            }
        }
    }
#pragma unroll
    for (int j = 0; j < 4; ++j) {
        if (j < nv) {
            int p = atomicAdd(&cursor[dd[j]], 1);
            csr_src[p] = (unsigned short)ss[j];
        }
    }
}

// ---- W pre-pad (both layers): [K][129] -> [K][132] + col-128 extract ----
__global__ void padw2_kernel(const float* __restrict__ W0, const float* __restrict__ W1,
                             float* __restrict__ Wp0, float* __restrict__ Wp1,
                             float* __restrict__ wcol0, float* __restrict__ wcol1) {
    int i = blockIdx.x * blockDim.x + threadIdx.x;
    const int TOT0 = 128 * 132;
    const int TOT1 = 129 * 132;
    if (i < TOT0) {
        int k = i / 132, c = i - k * 132;
        float v = (c < MID) ? W0[k * MID + c] : 0.f;
        Wp0[i] = v;
        if (c == 128) wcol0[k] = v;
    } else if (i < TOT0 + TOT1) {
        int ii = i - TOT0;
        int k = ii / 132, c = ii - k * 132;
        float v = (c < MID) ? W1[k * MID + c] : 0.f;
        Wp1[ii] = v;
        if (c == 128) wcol1[k] = v;
    }
}

// ---------------- GEMM (fp32 vector ALU, fp16 output) + fused attention logits ----------------
// block = 256 = 4 waves; 8 rows/wave; lane owns output cols {2l, 2l+1}; col 128 + al/ar via butterfly
template <int K>
__global__ void gemm_kernel(const float* __restrict__ X, const float* __restrict__ Xl,
                            const float* __restrict__ Wp, const float* __restrict__ wcol,
                            const float* __restrict__ asf, const float* __restrict__ adf,
                            _Float16* __restrict__ Hm16, float* __restrict__ Hl,
                            float* __restrict__ al, float* __restrict__ ar) {
    __shared__ float xs[32 * 132];
    __shared__ float Wc[132];
    int tid  = threadIdx.x;
    int row0 = blockIdx.x * 32;
    {
        int k = tid & 127;
        for (int rr = tid >> 7; rr < 32; rr += 2) {
            int row = row0 + rr;
            xs[rr * 132 + k] = (row < N_NODES) ? X[((size_t)row << 7) + k] : 0.f;
            if (k == 0)
                xs[rr * 132 + 128] = (K == 129 && row < N_NODES) ? Xl[row] : 0.f;
        }
        if (tid < K) Wc[tid] = wcol[tid];
    }
    __syncthreads();

    int wave = tid >> 6, lane = tid & 63;
    int c0 = 2 * lane, c1 = c0 + 1;
    int h0 = c0 / 43, h1 = c1 / 43;
    float as0 = asf[c0], as1 = asf[c1], ad0 = adf[c0], ad1 = adf[c1];
    float as128 = asf[128], ad128 = adf[128];

    const float* xbase = xs + wave * 8 * 132;
    float2 acc[8];
#pragma unroll
    for (int r = 0; r < 8; ++r) acc[r] = make_float2(0.f, 0.f);

    for (int k0 = 0; k0 < 128; k0 += 4) {
        float2 wv[4];
#pragma unroll
        for (int j = 0; j < 4; ++j)
            wv[j] = *(const float2*)(Wp + (k0 + j) * 132 + c0);
#pragma unroll
        for (int r = 0; r < 8; ++r) {
            float4 xq = *(const float4*)(xbase + r * 132 + k0);
            acc[r].x += xq.x * wv[0].x; acc[r].y += xq.x * wv[0].y;
            acc[r].x += xq.y * wv[1].x; acc[r].y += xq.y * wv[1].y;
            acc[r].x += xq.z * wv[2].x; acc[r].y += xq.z * wv[2].y;
            acc[r].x += xq.w * wv[3].x; acc[r].y += xq.w * wv[3].y;
        }
    }
    if (K == 129) {
        float2 wv = *(const float2*)(Wp + 128 * 132 + c0);
#pragma unroll
        for (int r = 0; r < 8; ++r) {
            float xv = xbase[r * 132 + 128];
            acc[r].x += xv * wv.x; acc[r].y += xv * wv.y;
        }
    }
#pragma unroll
    for (int r = 0; r < 8; ++r) {
        int row = row0 + wave * 8 + r;
        if (row < N_NODES) {
            half2v hv;
            hv[0] = (_Float16)acc[r].x;
            hv[1] = (_Float16)acc[r].y;
            *(half2v*)(Hm16 + ((size_t)row << 7) + c0) = hv;
        }
    }
    // fused epilogue per row: col-128 value + al/ar logits via one 7-value butterfly
#pragma unroll
    for (int r = 0; r < 8; ++r) {
        const float* xr = xbase + r * 132;
        float v[7];
        float plx = acc[r].x * as0, ply = acc[r].y * as1;
        float prx = acc[r].x * ad0, pry = acc[r].y * ad1;
#pragma unroll
        for (int h = 0; h < 3; ++h) {
            v[h]     = (h0 == h ? plx : 0.f) + (h1 == h ? ply : 0.f);
            v[3 + h] = (h0 == h ? prx : 0.f) + (h1 == h ? pry : 0.f);
        }
        v[6] = xr[lane] * Wc[lane] + xr[64 + lane] * Wc[64 + lane];
        if (K == 129 && lane == 0) v[6] += xr[128] * Wc[128];
#pragma unroll
        for (int off = 32; off; off >>= 1)
#pragma unroll
            for (int j = 0; j < 7; ++j) v[j] += __shfl_xor(v[j], off, 64);
        int row = row0 + wave * 8 + r;
        if (lane == 0 && row < N_NODES) {
            Hl[row] = v[6];
            al[row * 3]     = v[0];
            al[row * 3 + 1] = v[1];
            al[row * 3 + 2] = v[2] + v[6] * as128;
            ar[row * 3]     = v[3];
            ar[row * 3 + 1] = v[4];
            ar[row * 3 + 2] = v[5] + v[6] * ad128;
        }
    }
}

// ------- fused softmax + aggregation (129 ch, 3 heads), 4 edges/iter, fp16 gathers -------
template <bool ACT>
__global__ void agg129_kernel(const _Float16* __restrict__ Hm16, const float* __restrict__ Hl,
                              const float* __restrict__ al, const float* __restrict__ ar,
                              const int* __restrict__ rowp, const unsigned short* __restrict__ srcs,
                              const float* __restrict__ bias, float* __restrict__ Om,
                              float* __restrict__ Ol) {
    __shared__ float4 exs[4][64];
    int lane = threadIdx.x & 63;
    int wv   = threadIdx.x >> 6;
    int wid  = blockIdx.x * 4 + wv;
    if (wid >= N_NODES) return;

    int beg = rowp[wid], end = rowp[wid + 1];
    float ard0 = ar[wid * 3], ard1 = ar[wid * 3 + 1], ard2 = ar[wid * 3 + 2];

    int g  = lane >> 4;        // edge within quad
    int q  = lane & 15;        // channel group: channels 8q..8q+7
    int cb = 8 * q;

    bool bm0[8], bm1[8];
#pragma unroll
    for (int j = 0; j < 8; ++j) {
        bm0[j] = (cb + j) < 43;
        bm1[j] = (cb + j) < 86;
    }

    float accv[8];
#pragma unroll
    for (int j = 0; j < 8; ++j) accv[j] = 0.f;
    float acc128 = 0.f;
    float s0 = 0.f, s1 = 0.f, s2 = 0.f;
    float4* exw = exs[wv];

    for (int base = beg; base < end; base += 64) {
        int i = base + lane;
        float e0 = 0.f, e1 = 0.f, e2 = 0.f;
        int s = 0;
        if (i < end) {
            s = (int)srcs[i];
            const float* ap = al + s * 3;
            e0 = __expf(lrelu(ap[0] + ard0));
            e1 = __expf(lrelu(ap[1] + ard1));
            e2 = __expf(lrelu(ap[2] + ard2));
            s0 += e0; s1 += e1; s2 += e2;
        }
        exw[lane] = make_float4(e0, e1, e2, __int_as_float(s));
        int cnt = end - base; if (cnt > 64) cnt = 64;
        for (int t = 0; t < cnt; t += 4) {
            float4 ed = exw[t + g];              // zero-filled beyond cnt -> safe
            int ss = __float_as_int(ed.w);
            half8 hv = *(const half8*)(Hm16 + ((size_t)ss << 7) + cb);
            if (q == 0) acc128 += ed.z * Hl[ss];
#pragma unroll
            for (int j = 0; j < 8; ++j) {
                float w = bm0[j] ? ed.x : (bm1[j] ? ed.y : ed.z);
                accv[j] += w * (float)hv[j];
            }
        }
    }
#pragma unroll
    for (int off = 16; off <= 32; off <<= 1) {
#pragma unroll
        for (int j = 0; j < 8; ++j) accv[j] += __shfl_xor(accv[j], off, 64);
        acc128 += __shfl_xor(acc128, off, 64);
    }
#pragma unroll
    for (int off = 32; off; off >>= 1) {
        s0 += __shfl_xor(s0, off, 64);
        s1 += __shfl_xor(s1, off, 64);
        s2 += __shfl_xor(s2, off, 64);
    }
    float d0 = 1.f / (s0 + 1e-16f);
    float d1 = 1.f / (s1 + 1e-16f);
    float d2 = 1.f / (s2 + 1e-16f);
    if (g == 0) {
        float o[8];
        float4 bv0 = *(const float4*)(bias + cb);
        float4 bv1 = *(const float4*)(bias + cb + 4);
        float bb[8] = {bv0.x, bv0.y, bv0.z, bv0.w, bv1.x, bv1.y, bv1.z, bv1.w};
#pragma unroll
        for (int j = 0; j < 8; ++j) {
            float dv = bm0[j] ? d0 : (bm1[j] ? d1 : d2);
            o[j] = accv[j] * dv + bb[j];
            if (ACT) o[j] = lrelu(o[j]);
        }
        *(float4*)(Om + ((size_t)wid << 7) + cb)     = make_float4(o[0], o[1], o[2], o[3]);
        *(float4*)(Om + ((size_t)wid << 7) + cb + 4) = make_float4(o[4], o[5], o[6], o[7]);
        if (lane == 0) {
            float o128 = acc128 * d2 + bias[128];
            if (ACT) o128 = lrelu(o128);
            Ol[wid] = o128;
        }
    }
}

// ---------------- layer 2: fused GEMM (129->6) + logits, wave per node ----------------
__global__ void layer2_node_kernel(const float* __restrict__ Om, const float* __restrict__ Ol,
                                   const float* __restrict__ W2, const float* __restrict__ a2s,
                                   const float* __restrict__ a2d, float* __restrict__ H2,
                                   float* __restrict__ al2, float* __restrict__ ar2) {
    int lane = threadIdx.x & 63;
    int wid  = blockIdx.x * 4 + (threadIdx.x >> 6);
    if (wid >= N_NODES) return;
    int c0 = 2 * lane;
    float2 xv  = *(const float2*)(Om + ((size_t)wid << 7) + c0);
    float x128 = Ol[wid];
    const float* w0p = W2 + c0 * OUTC;
    const float* w1p = W2 + (c0 + 1) * OUTC;
    float m = (lane == 0) ? x128 : 0.f;
    float p[OUTC];
#pragma unroll
    for (int c = 0; c < OUTC; ++c)
        p[c] = xv.x * w0p[c] + xv.y * w1p[c] + m * W2[128 * OUTC + c];
#pragma unroll
    for (int off = 32; off; off >>= 1)
#pragma unroll
        for (int c = 0; c < OUTC; ++c) p[c] += __shfl_xor(p[c], off, 64);
    float sl = 0.f, sr = 0.f;
#pragma unroll
    for (int c = 0; c < OUTC; ++c) { sl += p[c] * a2s[c]; sr += p[c] * a2d[c]; }
    if (lane == 0) {
#pragma unroll
        for (int c = 0; c < OUTC; ++c) H2[wid * OUTC + c] = p[c];
        al2[wid] = sl;
        ar2[wid] = sr;
    }
}

// ---------------- layer 2 aggregate (1 head, 6 ch), 8 edges/iter ----------------
__global__ void agg6_kernel(const float* __restrict__ H2, const float* __restrict__ al2,
                            const float* __restrict__ ar2, const int* __restrict__ rowp,
                            const unsigned short* __restrict__ srcs, const float* __restrict__ b2,
                            float* __restrict__ out) {
    __shared__ float2 exs[4][64];
    int lane = threadIdx.x & 63;
    int wv   = threadIdx.x >> 6;
    int wid  = blockIdx.x * 4 + wv;
    if (wid >= N_NODES) return;
    int beg = rowp[wid], end = rowp[wid + 1];
    float ard = ar2[wid];
    int grp = lane >> 3;
    int myc = lane & 7;
    int cc  = (myc < OUTC) ? myc : 0;
    float ssum = 0.f, acc = 0.f;
    float2* exw = exs[wv];
    for (int base = beg; base < end; base += 64) {
        int i = base + lane;
        float ex = 0.f;
        int s = 0;
        if (i < end) {
            s = (int)srcs[i];
            ex = __expf(lrelu(al2[s] + ard));
            ssum += ex;
        }
        exw[lane] = make_float2(ex, __int_as_float(s));
        int cnt = end - base; if (cnt > 64) cnt = 64;
        for (int t = 0; t < cnt; t += 8) {
            float2 ed = exw[t + grp];
            int ss = __float_as_int(ed.y);
            acc += ed.x * H2[ss * OUTC + cc];
        }
    }
    acc += __shfl_xor(acc, 8, 64);
    acc += __shfl_xor(acc, 16, 64);
    acc += __shfl_xor(acc, 32, 64);
#pragma unroll
    for (int off = 32; off; off >>= 1) ssum += __shfl_xor(ssum, off, 64);
    float dinv = 1.f / (ssum + 1e-16f);
    if (lane < OUTC) out[(size_t)wid * OUTC + lane] = acc * dinv + b2[lane];
}

// ---------------- launch ----------------

extern "C" void kernel_launch(void* const* d_in, const int* in_sizes, int n_in,
                              void* d_out, int out_size, void* d_ws, size_t ws_size,
                              hipStream_t stream) {
    const float* x   = (const float*)d_in[0];
    const int*   ei  = (const int*)d_in[1];
    const float* W0  = (const float*)d_in[2];
    const float* a0s = (const float*)d_in[3];
    const float* a0d = (const float*)d_in[4];
    const float* b0  = (const float*)d_in[5];
    const float* W1  = (const float*)d_in[6];
    const float* a1s = (const float*)d_in[7];
    const float* a1d = (const float*)d_in[8];
    const float* b1  = (const float*)d_in[9];
    const float* W2  = (const float*)d_in[10];
    const float* a2s = (const float*)d_in[11];
    const float* a2d = (const float*)d_in[12];
    const float* b2  = (const float*)d_in[13];
    float* out = (float*)d_out;

    char* p = (char*)d_ws;
    auto take = [&](size_t bytes) -> void* {
        void* r = (void*)p;
        p += (bytes + 255) & ~(size_t)255;
        return r;
    };
    int*            cnt     = (int*)take((size_t)N_NODES * 4);
    int*            rowp    = (int*)take((size_t)(N_NODES + 1) * 4);
    int*            cursor  = (int*)take((size_t)N_NODES * 4);
    unsigned short* csr_src = (unsigned short*)take((size_t)ET * 2);
    float*          al      = (float*)take((size_t)N_NODES * 3 * 4);
    float*          ar      = (float*)take((size_t)N_NODES * 3 * 4);
    _Float16*       Hm16    = (_Float16*)take((size_t)N_NODES * 128 * 2);
    float*          Hl      = (float*)take((size_t)N_NODES * 4);
    float*          Om      = (float*)take((size_t)N_NODES * 128 * 4);
    float*          Ol      = (float*)take((size_t)N_NODES * 4);
    float*          Wp0     = (float*)take((size_t)128 * 132 * 4);
    float*          Wp1     = (float*)take((size_t)129 * 132 * 4);
    float*          wcol0   = (float*)take((size_t)128 * 4);
    float*          wcol1   = (float*)take((size_t)129 * 4);
    float*          H2      = (float*)take((size_t)N_NODES * OUTC * 4);

    const int* esrc = ei;
    const int* edst = ei + N_EDGES;

    hipMemsetAsync(cnt, 0, (size_t)N_NODES * 4, stream);
    count_kernel<<<((ET + 1) / 2 + 255) / 256, 256, 0, stream>>>(edst, cnt);
    scan_kernel<<<1, 1024, 0, stream>>>(cnt, rowp, cursor);
    scatter_kernel<<<((ET + 3) / 4 + 255) / 256, 256, 0, stream>>>(esrc, edst, cursor, csr_src);

    padw2_kernel<<<((128 + 129) * 132 + 255) / 256, 256, 0, stream>>>(W0, W1, Wp0, Wp1, wcol0, wcol1);

    const int gemm_grid = (N_NODES + 31) / 32;
    const int node_grid = (N_NODES + 3) / 4;

    // layer 0 (alar fused into gemm epilogue)
    gemm_kernel<128><<<gemm_grid, 256, 0, stream>>>(x, x, Wp0, wcol0, a0s, a0d, Hm16, Hl, al, ar);
    agg129_kernel<true><<<node_grid, 256, 0, stream>>>(Hm16, Hl, al, ar, rowp, csr_src, b0, Om, Ol);

    // layer 1
    gemm_kernel<129><<<gemm_grid, 256, 0, stream>>>(Om, Ol, Wp1, wcol1, a1s, a1d, Hm16, Hl, al, ar);
    agg129_kernel<true><<<node_grid, 256, 0, stream>>>(Hm16, Hl, al, ar, rowp, csr_src, b1, Om, Ol);

    // layer 2
    layer2_node_kernel<<<node_grid, 256, 0, stream>>>(Om, Ol, W2, a2s, a2d, H2, al, ar);
    agg6_kernel<<<node_grid, 256, 0, stream>>>(H2, al, ar, rowp, csr_src, b2, out);
}

// Round 6
// 375.423 us; speedup vs baseline: 1.8886x; 1.1687x over previous
//
#include <hip/hip_runtime.h>

#define N_NODES 50000
#define N_EDGES 800000
#define ET (N_EDGES + N_NODES)   // edges + self loops = 850000
#define MID 129
#define OUTC 6

typedef _Float16 half2v __attribute__((ext_vector_type(2)));
typedef _Float16 half8  __attribute__((ext_vector_type(8)));
typedef float    floatx4 __attribute__((ext_vector_type(4)));

__device__ __forceinline__ float lrelu(float x) { return x > 0.f ? x : 0.2f * x; }

// ---------------- CSR build ----------------

__global__ void count_kernel(const int* __restrict__ dst, int* __restrict__ cnt) {
    int e0 = (blockIdx.x * blockDim.x + threadIdx.x) * 2;
    if (e0 >= ET) return;
    if (e0 + 2 <= N_EDGES) {
        int2 a = *(const int2*)(dst + e0);
        atomicAdd(&cnt[a.x], 1);
        atomicAdd(&cnt[a.y], 1);
    } else {
#pragma unroll
        for (int j = 0; j < 2; ++j) {
            int e = e0 + j;
            if (e < ET) {
                int d = (e < N_EDGES) ? dst[e] : (e - N_EDGES);
                atomicAdd(&cnt[d], 1);
            }
        }
    }
}

// single-block exclusive scan, 4 elements/thread
__global__ void scan_kernel(const int* __restrict__ cnt, int* __restrict__ row,
                            int* __restrict__ cursor) {
    __shared__ int wsum[16];
    __shared__ int carry_s;
    int tid  = threadIdx.x;
    int lane = tid & 63;
    int wv   = tid >> 6;
    if (tid == 0) carry_s = 0;
    __syncthreads();
    for (int base = 0; base < N_NODES; base += 4096) {
        int i0 = base + tid * 4;
        int v0 = 0, v1 = 0, v2 = 0, v3 = 0;
        if (i0 + 3 < N_NODES) {
            const int4 q = *(const int4*)(cnt + i0);
            v0 = q.x; v1 = q.y; v2 = q.z; v3 = q.w;
        } else {
            if (i0     < N_NODES) v0 = cnt[i0];
            if (i0 + 1 < N_NODES) v1 = cnt[i0 + 1];
            if (i0 + 2 < N_NODES) v2 = cnt[i0 + 2];
            if (i0 + 3 < N_NODES) v3 = cnt[i0 + 3];
        }
        int t = v0 + v1 + v2 + v3;
        int x = t;
#pragma unroll
        for (int off = 1; off < 64; off <<= 1) {
            int sh = __shfl_up(x, off, 64);
            if (lane >= off) x += sh;
        }
        if (lane == 63) wsum[wv] = x;
        __syncthreads();
        if (wv == 0) {
            int w = (lane < 16) ? wsum[lane] : 0;
#pragma unroll
            for (int off = 1; off < 16; off <<= 1) {
                int sh = __shfl_up(w, off, 64);
                if (lane >= off) w += sh;
            }
            if (lane < 16) wsum[lane] = w;
        }
        __syncthreads();
        int wexcl = wv ? wsum[wv - 1] : 0;
        int total = wsum[15];
        int c0    = carry_s;
        __syncthreads();
        int e = c0 + wexcl + (x - t);
        if (i0     < N_NODES) { row[i0]     = e; cursor[i0]     = e; } e += v0;
        if (i0 + 1 < N_NODES) { row[i0 + 1] = e; cursor[i0 + 1] = e; } e += v1;
        if (i0 + 2 < N_NODES) { row[i0 + 2] = e; cursor[i0 + 2] = e; } e += v2;
        if (i0 + 3 < N_NODES) { row[i0 + 3] = e; cursor[i0 + 3] = e; }
        if (tid == 0) carry_s = c0 + total;
        __syncthreads();
    }
    if (tid == 0) row[N_NODES] = carry_s;
}

__global__ void scatter_kernel(const int* __restrict__ src, const int* __restrict__ dst,
                               int* __restrict__ cursor, unsigned short* __restrict__ csr_src) {
    int e0 = (blockIdx.x * blockDim.x + threadIdx.x) * 4;
    if (e0 >= ET) return;
    int ss[4], dd[4];
    int nv = 4;
    if (e0 + 4 <= N_EDGES) {
        int4 a = *(const int4*)(src + e0);
        ss[0] = a.x; ss[1] = a.y; ss[2] = a.z; ss[3] = a.w;
        int4 c = *(const int4*)(dst + e0);
        dd[0] = c.x; dd[1] = c.y; dd[2] = c.z; dd[3] = c.w;
    } else {
        nv = 0;
#pragma unroll
        for (int j = 0; j < 4; ++j) {
            int e = e0 + j;
            if (e < ET) {
                if (e < N_EDGES) { ss[j] = src[e]; dd[j] = dst[e]; }
                else             { ss[j] = dd[j] = e - N_EDGES; }
                nv = j + 1;
            }
        }
    }
#pragma unroll
    for (int j = 0; j < 4; ++j) {
        if (j < nv) {
            int p = atomicAdd(&cursor[dd[j]], 1);
            csr_src[p] = (unsigned short)ss[j];
        }
    }
}

// ---------------- x -> fp16 convert ----------------
__global__ void convx_kernel(const float* __restrict__ X, _Float16* __restrict__ Xh) {
    int i = (blockIdx.x * blockDim.x + threadIdx.x) * 8;
    if (i >= N_NODES * 128) return;
    float4 a = *(const float4*)(X + i);
    float4 b = *(const float4*)(X + i + 4);
    half8 h;
    h[0] = (_Float16)a.x; h[1] = (_Float16)a.y; h[2] = (_Float16)a.z; h[3] = (_Float16)a.w;
    h[4] = (_Float16)b.x; h[5] = (_Float16)b.y; h[6] = (_Float16)b.z; h[7] = (_Float16)b.w;
    *(half8*)(Xh + i) = h;
}

// ---- Build MFMA weight blocks: Wt[l][144][128] fp16 (n-major, k-minor) ----
// cols 0..128 = W^T; 129..131 = A_src (W @ a_src per head); 132..134 = A_dst; rest 0.
// Also w128row1[144] fp32: layer-1 k=128 row (rank-1 epilogue), same column schema.
__global__ void padw_kernel(const float* __restrict__ W0, const float* __restrict__ a0s,
                            const float* __restrict__ a0d, const float* __restrict__ W1,
                            const float* __restrict__ a1s, const float* __restrict__ a1d,
                            _Float16* __restrict__ Wt0, _Float16* __restrict__ Wt1,
                            float* __restrict__ w128row1) {
    const int SEG = 144 * 128;
    int i = blockIdx.x * blockDim.x + threadIdx.x;
    if (i < 2 * SEG) {
        int l = i / SEG;
        int ii = i - l * SEG;
        int n = ii >> 7, k = ii & 127;
        const float* W = l ? W1 : W0;
        const float* as = l ? a1s : a0s;
        const float* ad = l ? a1d : a0d;
        float v = 0.f;
        if (n < 129) v = W[k * MID + n];
        else if (n < 132) {
            int h = n - 129;
            float sum = 0.f;
            for (int c = 0; c < 43; ++c) sum += W[k * MID + 43 * h + c] * as[43 * h + c];
            v = sum;
        } else if (n < 135) {
            int h = n - 132;
            float sum = 0.f;
            for (int c = 0; c < 43; ++c) sum += W[k * MID + 43 * h + c] * ad[43 * h + c];
            v = sum;
        }
        (l ? Wt1 : Wt0)[ii] = (_Float16)v;
    } else if (i < 2 * SEG + 144) {
        int n = i - 2 * SEG;
        float v = 0.f;
        if (n < 129) v = W1[128 * MID + n];
        else if (n < 132) {
            int h = n - 129;
            float sum = 0.f;
            for (int c = 0; c < 43; ++c) sum += W1[128 * MID + 43 * h + c] * a1s[43 * h + c];
            v = sum;
        } else if (n < 135) {
            int h = n - 132;
            float sum = 0.f;
            for (int c = 0; c < 43; ++c) sum += W1[128 * MID + 43 * h + c] * a1d[43 * h + c];
            v = sum;
        }
        w128row1[n] = v;
    }
}

// ---------------- MFMA GEMM + fused logits ----------------
// D[m][n] = X[m][:128] @ Wt[n][:128]; wave = one 16-row m-tile x 3 n-tiles (48 cols).
// A frag: X[row0+ (lane&15)][kt*32 + (lane>>4)*8 + j]; B frag: Wt[n][same k]; D: col=lane&15, row=quad*4+reg.
// RANK1 adds Xl[row]*w128[n] (layer-1 k=128 channel) in fp32 epilogue.
template <bool RANK1>
__global__ __launch_bounds__(256)
void gemm_mfma_kernel(const _Float16* __restrict__ Xh, const float* __restrict__ Xl,
                      const _Float16* __restrict__ Wt, const float* __restrict__ w128,
                      _Float16* __restrict__ Hm16, float* __restrict__ Hl,
                      float* __restrict__ al, float* __restrict__ ar) {
    int wave = threadIdx.x >> 6, lane = threadIdx.x & 63;
    int mt = blockIdx.x * 4 + wave;
    if (mt * 16 >= N_NODES) return;
    int t = lane & 15, quad = lane >> 4;
    int row0 = mt * 16;

    const _Float16* arow = Xh + ((size_t)(row0 + t) << 7) + quad * 8;
    half8 af[4];
#pragma unroll
    for (int kt = 0; kt < 4; ++kt) af[kt] = *(const half8*)(arow + kt * 32);

    floatx4 acc[3];
#pragma unroll
    for (int nt = 0; nt < 3; ++nt) {
        int ntile = blockIdx.y * 3 + nt;
        const _Float16* brow = Wt + ((size_t)(ntile * 16 + t) << 7) + quad * 8;
        floatx4 a = {0.f, 0.f, 0.f, 0.f};
#pragma unroll
        for (int kt = 0; kt < 4; ++kt) {
            half8 b = *(const half8*)(brow + kt * 32);
            a = __builtin_amdgcn_mfma_f32_16x16x32_f16(af[kt], b, a, 0, 0, 0);
        }
        acc[nt] = a;
    }

#pragma unroll
    for (int r = 0; r < 4; ++r) {
        int row = row0 + quad * 4 + r;
        float xl = RANK1 ? Xl[row] : 0.f;
#pragma unroll
        for (int nt = 0; nt < 3; ++nt) {
            int n = (blockIdx.y * 3 + nt) * 16 + t;
            float v = acc[nt][r];
            if (RANK1) v += xl * w128[n];
            if (n < 128) {
                Hm16[((size_t)row << 7) + n] = (_Float16)v;
            } else if (n == 128) {
                Hl[row] = v;
            } else if (n < 132) {
                al[row * 3 + (n - 129)] = v;
            } else if (n < 135) {
                ar[row * 3 + (n - 132)] = v;
            }
        }
    }
}

// ------- fused softmax + aggregation (129 ch, 3 heads), 4 edges/iter, fp16 gathers -------
template <bool ACT>
__global__ void agg129_kernel(const _Float16* __restrict__ Hm16, const float* __restrict__ Hl,
                              const float* __restrict__ al, const float* __restrict__ ar,
                              const int* __restrict__ rowp, const unsigned short* __restrict__ srcs,
                              const float* __restrict__ bias, _Float16* __restrict__ Omh,
                              float* __restrict__ Ol) {
    __shared__ float4 exs[4][64];
    int lane = threadIdx.x & 63;
    int wv   = threadIdx.x >> 6;
    int wid  = blockIdx.x * 4 + wv;
    if (wid >= N_NODES) return;

    int beg = rowp[wid], end = rowp[wid + 1];
    float ard0 = ar[wid * 3], ard1 = ar[wid * 3 + 1], ard2 = ar[wid * 3 + 2];

    int g  = lane >> 4;        // edge within quad
    int q  = lane & 15;        // channel group: channels 8q..8q+7
    int cb = 8 * q;

    bool bm0[8], bm1[8];
#pragma unroll
    for (int j = 0; j < 8; ++j) {
        bm0[j] = (cb + j) < 43;
        bm1[j] = (cb + j) < 86;
    }

    float accv[8];
#pragma unroll
    for (int j = 0; j < 8; ++j) accv[j] = 0.f;
    float acc128 = 0.f;
    float s0 = 0.f, s1 = 0.f, s2 = 0.f;
    float4* exw = exs[wv];

    for (int base = beg; base < end; base += 64) {
        int i = base + lane;
        float e0 = 0.f, e1 = 0.f, e2 = 0.f;
        int s = 0;
        if (i < end) {
            s = (int)srcs[i];
            const float* ap = al + s * 3;
            e0 = __expf(lrelu(ap[0] + ard0));
            e1 = __expf(lrelu(ap[1] + ard1));
            e2 = __expf(lrelu(ap[2] + ard2));
            s0 += e0; s1 += e1; s2 += e2;
        }
        exw[lane] = make_float4(e0, e1, e2, __int_as_float(s));
        int cnt = end - base; if (cnt > 64) cnt = 64;
        for (int tt = 0; tt < cnt; tt += 4) {
            float4 ed = exw[tt + g];             // zero-filled beyond cnt -> safe
            int ss = __float_as_int(ed.w);
            half8 hv = *(const half8*)(Hm16 + ((size_t)ss << 7) + cb);
            if (q == 0) acc128 += ed.z * Hl[ss];
#pragma unroll
            for (int j = 0; j < 8; ++j) {
                float w = bm0[j] ? ed.x : (bm1[j] ? ed.y : ed.z);
                accv[j] += w * (float)hv[j];
            }
        }
    }
#pragma unroll
    for (int off = 16; off <= 32; off <<= 1) {
#pragma unroll
        for (int j = 0; j < 8; ++j) accv[j] += __shfl_xor(accv[j], off, 64);
        acc128 += __shfl_xor(acc128, off, 64);
    }
#pragma unroll
    for (int off = 32; off; off >>= 1) {
        s0 += __shfl_xor(s0, off, 64);
        s1 += __shfl_xor(s1, off, 64);
        s2 += __shfl_xor(s2, off, 64);
    }
    float d0 = 1.f / (s0 + 1e-16f);
    float d1 = 1.f / (s1 + 1e-16f);
    float d2 = 1.f / (s2 + 1e-16f);
    if (g == 0) {
        float4 bv0 = *(const float4*)(bias + cb);
        float4 bv1 = *(const float4*)(bias + cb + 4);
        float bb[8] = {bv0.x, bv0.y, bv0.z, bv0.w, bv1.x, bv1.y, bv1.z, bv1.w};
        half8 oh;
#pragma unroll
        for (int j = 0; j < 8; ++j) {
            float dv = bm0[j] ? d0 : (bm1[j] ? d1 : d2);
            float o = accv[j] * dv + bb[j];
            if (ACT) o = lrelu(o);
            oh[j] = (_Float16)o;
        }
        *(half8*)(Omh + ((size_t)wid << 7) + cb) = oh;
        if (lane == 0) {
            float o128 = acc128 * d2 + bias[128];
            if (ACT) o128 = lrelu(o128);
            Ol[wid] = o128;
        }
    }
}

// ---------------- layer 2: fused GEMM (129->6) + logits, wave per node ----------------
__global__ void layer2_node_kernel(const _Float16* __restrict__ Omh, const float* __restrict__ Ol,
                                   const float* __restrict__ W2, const float* __restrict__ a2s,
                                   const float* __restrict__ a2d, float* __restrict__ H2,
                                   float* __restrict__ al2, float* __restrict__ ar2) {
    int lane = threadIdx.x & 63;
    int wid  = blockIdx.x * 4 + (threadIdx.x >> 6);
    if (wid >= N_NODES) return;
    int c0 = 2 * lane;
    half2v xv = *(const half2v*)(Omh + ((size_t)wid << 7) + c0);
    float xx = (float)xv[0], xy = (float)xv[1];
    float x128 = Ol[wid];
    const float* w0p = W2 + c0 * OUTC;
    const float* w1p = W2 + (c0 + 1) * OUTC;
    float m = (lane == 0) ? x128 : 0.f;
    float p[OUTC];
#pragma unroll
    for (int c = 0; c < OUTC; ++c)
        p[c] = xx * w0p[c] + xy * w1p[c] + m * W2[128 * OUTC + c];
#pragma unroll
    for (int off = 32; off; off >>= 1)
#pragma unroll
        for (int c = 0; c < OUTC; ++c) p[c] += __shfl_xor(p[c], off, 64);
    float sl = 0.f, sr = 0.f;
#pragma unroll
    for (int c = 0; c < OUTC; ++c) { sl += p[c] * a2s[c]; sr += p[c] * a2d[c]; }
    if (lane == 0) {
#pragma unroll
        for (int c = 0; c < OUTC; ++c) H2[wid * OUTC + c] = p[c];
        al2[wid] = sl;
        ar2[wid] = sr;
    }
}

// ---------------- layer 2 aggregate (1 head, 6 ch), 8 edges/iter ----------------
__global__ void agg6_kernel(const float* __restrict__ H2, const float* __restrict__ al2,
                            const float* __restrict__ ar2, const int* __restrict__ rowp,
                            const unsigned short* __restrict__ srcs, const float* __restrict__ b2,
                            float* __restrict__ out) {
    __shared__ float2 exs[4][64];
    int lane = threadIdx.x & 63;
    int wv   = threadIdx.x >> 6;
    int wid  = blockIdx.x * 4 + wv;
    if (wid >= N_NODES) return;
    int beg = rowp[wid], end = rowp[wid + 1];
    float ard = ar2[wid];
    int grp = lane >> 3;
    int myc = lane & 7;
    int cc  = (myc < OUTC) ? myc : 0;
    float ssum = 0.f, acc = 0.f;
    float2* exw = exs[wv];
    for (int base = beg; base < end; base += 64) {
        int i = base + lane;
        float ex = 0.f;
        int s = 0;
        if (i < end) {
            s = (int)srcs[i];
            ex = __expf(lrelu(al2[s] + ard));
            ssum += ex;
        }
        exw[lane] = make_float2(ex, __int_as_float(s));
        int cnt = end - base; if (cnt > 64) cnt = 64;
        for (int t = 0; t < cnt; t += 8) {
            float2 ed = exw[t + grp];
            int ss = __float_as_int(ed.y);
            acc += ed.x * H2[ss * OUTC + cc];
        }
    }
    acc += __shfl_xor(acc, 8, 64);
    acc += __shfl_xor(acc, 16, 64);
    acc += __shfl_xor(acc, 32, 64);
#pragma unroll
    for (int off = 32; off; off >>= 1) ssum += __shfl_xor(ssum, off, 64);
    float dinv = 1.f / (ssum + 1e-16f);
    if (lane < OUTC) out[(size_t)wid * OUTC + lane] = acc * dinv + b2[lane];
}

// ---------------- launch ----------------

extern "C" void kernel_launch(void* const* d_in, const int* in_sizes, int n_in,
                              void* d_out, int out_size, void* d_ws, size_t ws_size,
                              hipStream_t stream) {
    const float* x   = (const float*)d_in[0];
    const int*   ei  = (const int*)d_in[1];
    const float* W0  = (const float*)d_in[2];
    const float* a0s = (const float*)d_in[3];
    const float* a0d = (const float*)d_in[4];
    const float* b0  = (const float*)d_in[5];
    const float* W1  = (const float*)d_in[6];
    const float* a1s = (const float*)d_in[7];
    const float* a1d = (const float*)d_in[8];
    const float* b1  = (const float*)d_in[9];
    const float* W2  = (const float*)d_in[10];
    const float* a2s = (const float*)d_in[11];
    const float* a2d = (const float*)d_in[12];
    const float* b2  = (const float*)d_in[13];
    float* out = (float*)d_out;

    char* p = (char*)d_ws;
    auto take = [&](size_t bytes) -> void* {
        void* r = (void*)p;
        p += (bytes + 255) & ~(size_t)255;
        return r;
    };
    int*            cnt      = (int*)take((size_t)N_NODES * 4);
    int*            rowp     = (int*)take((size_t)(N_NODES + 1) * 4);
    int*            cursor   = (int*)take((size_t)N_NODES * 4);
    unsigned short* csr_src  = (unsigned short*)take((size_t)ET * 2);
    float*          al       = (float*)take((size_t)N_NODES * 3 * 4);
    float*          ar       = (float*)take((size_t)N_NODES * 3 * 4);
    _Float16*       Xh16     = (_Float16*)take((size_t)N_NODES * 128 * 2);
    _Float16*       Hm16     = (_Float16*)take((size_t)N_NODES * 128 * 2);
    _Float16*       Omh      = (_Float16*)take((size_t)N_NODES * 128 * 2);
    float*          Hl       = (float*)take((size_t)N_NODES * 4);
    float*          Ol       = (float*)take((size_t)N_NODES * 4);
    _Float16*       Wt0      = (_Float16*)take((size_t)144 * 128 * 2);
    _Float16*       Wt1      = (_Float16*)take((size_t)144 * 128 * 2);
    float*          w128row1 = (float*)take((size_t)144 * 4);
    float*          H2       = (float*)take((size_t)N_NODES * OUTC * 4);

    const int* esrc = ei;
    const int* edst = ei + N_EDGES;

    // CSR build
    hipMemsetAsync(cnt, 0, (size_t)N_NODES * 4, stream);
    count_kernel<<<((ET + 1) / 2 + 255) / 256, 256, 0, stream>>>(edst, cnt);
    scan_kernel<<<1, 1024, 0, stream>>>(cnt, rowp, cursor);
    scatter_kernel<<<((ET + 3) / 4 + 255) / 256, 256, 0, stream>>>(esrc, edst, cursor, csr_src);

    // preprocessing for MFMA gemms
    convx_kernel<<<(N_NODES * 128 / 8 + 255) / 256, 256, 0, stream>>>(x, Xh16);
    padw_kernel<<<(2 * 144 * 128 + 144 + 255) / 256, 256, 0, stream>>>(
        W0, a0s, a0d, W1, a1s, a1d, Wt0, Wt1, w128row1);

    const dim3 gemm_grid((N_NODES / 16 + 3) / 4, 3);
    const int  node_grid = (N_NODES + 3) / 4;

    // layer 0: MFMA gemm emits Hm16 + Hl + al/ar directly
    gemm_mfma_kernel<false><<<gemm_grid, 256, 0, stream>>>(Xh16, Ol, Wt0, w128row1, Hm16, Hl, al, ar);
    agg129_kernel<true><<<node_grid, 256, 0, stream>>>(Hm16, Hl, al, ar, rowp, csr_src, b0, Omh, Ol);

    // layer 1: K=128 MFMA + rank-1 (col-128) epilogue
    gemm_mfma_kernel<true><<<gemm_grid, 256, 0, stream>>>(Omh, Ol, Wt1, w128row1, Hm16, Hl, al, ar);
    agg129_kernel<true><<<node_grid, 256, 0, stream>>>(Hm16, Hl, al, ar, rowp, csr_src, b1, Omh, Ol);

    // layer 2
    layer2_node_kernel<<<node_grid, 256, 0, stream>>>(Omh, Ol, W2, a2s, a2d, H2, al, ar);
    agg6_kernel<<<node_grid, 256, 0, stream>>>(H2, al, ar, rowp, csr_src, b2, out);
}

// Round 7
// 305.775 us; speedup vs baseline: 2.3188x; 1.2278x over previous
//
#include <hip/hip_runtime.h>

#define N_NODES 50000
#define N_EDGES 800000
#define ET (N_EDGES + N_NODES)   // edges + self loops = 850000
#define MID 129
#define OUTC 6
#define NB 196                   // coarse buckets: dst >> 8  (50000/256 -> 0..195)
#define CT 4096                  // edges per coarse-scatter block

typedef _Float16 half2v __attribute__((ext_vector_type(2)));
typedef _Float16 half8  __attribute__((ext_vector_type(8)));
typedef float    floatx4 __attribute__((ext_vector_type(4)));

__device__ __forceinline__ float lrelu(float x) { return x > 0.f ? x : 0.2f * x; }

// ---------------- CSR build: two-phase bin sort ----------------

__global__ void ccount_kernel(const int* __restrict__ dst, int* __restrict__ ccnt) {
    __shared__ int lh[NB];
    for (int i = threadIdx.x; i < NB; i += 256) lh[i] = 0;
    __syncthreads();
    int base = blockIdx.x * CT;
#pragma unroll 4
    for (int j = 0; j < CT; j += 256) {
        int e = base + j + threadIdx.x;
        if (e < ET) {
            int d = (e < N_EDGES) ? dst[e] : (e - N_EDGES);
            atomicAdd(&lh[d >> 8], 1);
        }
    }
    __syncthreads();
    for (int i = threadIdx.x; i < NB; i += 256) {
        int v = lh[i];
        if (v) atomicAdd(&ccnt[i], v);
    }
}

__global__ void cscan_kernel(const int* __restrict__ ccnt, int* __restrict__ cbase,
                             int* __restrict__ ccur) {
    __shared__ int buf[256];
    int t = threadIdx.x;
    buf[t] = (t < NB) ? ccnt[t] : 0;
    __syncthreads();
    for (int off = 1; off < 256; off <<= 1) {
        int v = (t >= off) ? buf[t - off] : 0;
        __syncthreads();
        buf[t] += v;
        __syncthreads();
    }
    int excl = t ? buf[t - 1] : 0;
    if (t < NB) { cbase[t] = excl; ccur[t] = excl; }
    if (t == NB - 1) cbase[NB] = buf[t];
}

// stage 4096 edges in LDS grouped by coarse bucket, then copy out bucket-contiguous segments
__global__ void cscatter_kernel(const int* __restrict__ src, const int* __restrict__ dst,
                                int* __restrict__ ccur, unsigned int* __restrict__ cval) {
    __shared__ unsigned int staged[CT];
    __shared__ int lh[NB], lex[NB], lcur[NB], lgb[NB];
    __shared__ int sbuf[256];
    int tid = threadIdx.x;
    for (int i = tid; i < NB; i += 256) lh[i] = 0;
    __syncthreads();
    int base = blockIdx.x * CT;
    unsigned int myv[16];
    int myb[16];
    int myn = 0;
#pragma unroll
    for (int j = 0; j < 16; ++j) {
        int e = base + j * 256 + tid;
        if (e < ET) {
            int s, d;
            if (e < N_EDGES) { s = src[e]; d = dst[e]; }
            else             { s = d = e - N_EDGES; }
            int b = d >> 8;
            myv[j] = ((unsigned)b << 24) | ((unsigned)(d & 255) << 16) | (unsigned)s;
            myb[j] = b;
            atomicAdd(&lh[b], 1);
            myn = j + 1;
        }
    }
    __syncthreads();
    sbuf[tid] = (tid < NB) ? lh[tid] : 0;
    __syncthreads();
    for (int off = 1; off < 256; off <<= 1) {
        int v = (tid >= off) ? sbuf[tid - off] : 0;
        __syncthreads();
        sbuf[tid] += v;
        __syncthreads();
    }
    if (tid < NB) {
        int excl = tid ? sbuf[tid - 1] : 0;
        lex[tid] = excl;
        lcur[tid] = excl;
    }
    __syncthreads();
    for (int j = 0; j < myn; ++j) {
        int p = atomicAdd(&lcur[myb[j]], 1);
        staged[p] = myv[j];
    }
    __syncthreads();
    if (tid < NB) {
        int c = lh[tid];
        lgb[tid] = c ? atomicAdd(&ccur[tid], c) : 0;
    }
    __syncthreads();
    int tot = ET - base; if (tot > CT) tot = CT;
    for (int i = tid; i < tot; i += 256) {
        unsigned int v = staged[i];
        int b = v >> 24;
        cval[lgb[b] + (i - lex[b])] = v;
    }
}

// one block per coarse bucket: 256-bin counting sort; writes csr_src + rowp
__global__ __launch_bounds__(512)
void fine_kernel(const unsigned int* __restrict__ cval, const int* __restrict__ cbase,
                 int* __restrict__ rowp, unsigned short* __restrict__ csr_src) {
    __shared__ int h[256], cur[256], sb[256];
    int b = blockIdx.x;
    int beg = cbase[b], end = cbase[b + 1];
    int t = threadIdx.x;
    if (t < 256) h[t] = 0;
    __syncthreads();
    for (int i = beg + t; i < end; i += 512)
        atomicAdd(&h[(cval[i] >> 16) & 255], 1);
    __syncthreads();
    if (t < 256) sb[t] = h[t];
    __syncthreads();
    for (int off = 1; off < 256; off <<= 1) {
        int v = 0;
        if (t < 256 && t >= off) v = sb[t - off];
        __syncthreads();
        if (t < 256) sb[t] += v;
        __syncthreads();
    }
    if (t < 256) {
        int excl = t ? sb[t - 1] : 0;
        cur[t] = excl;
        int dstv = (b << 8) + t;
        if (dstv <= N_NODES) rowp[dstv] = beg + excl;   // dstv==N_NODES -> rowp[N]=ET
    }
    __syncthreads();
    for (int i = beg + t; i < end; i += 512) {
        unsigned int v = cval[i];
        int low = (v >> 16) & 255;
        int p = atomicAdd(&cur[low], 1);
        csr_src[beg + p] = (unsigned short)(v & 0xFFFFu);
    }
}

// ---------------- x -> fp16 convert ----------------
__global__ void convx_kernel(const float* __restrict__ X, _Float16* __restrict__ Xh) {
    int i = (blockIdx.x * blockDim.x + threadIdx.x) * 8;
    if (i >= N_NODES * 128) return;
    float4 a = *(const float4*)(X + i);
    float4 b = *(const float4*)(X + i + 4);
    half8 h;
    h[0] = (_Float16)a.x; h[1] = (_Float16)a.y; h[2] = (_Float16)a.z; h[3] = (_Float16)a.w;
    h[4] = (_Float16)b.x; h[5] = (_Float16)b.y; h[6] = (_Float16)b.z; h[7] = (_Float16)b.w;
    *(half8*)(Xh + i) = h;
}

// ---- Build MFMA weight blocks: Wt[l][144][128] fp16 (n-major, k-minor) ----
__global__ void padw_kernel(const float* __restrict__ W0, const float* __restrict__ a0s,
                            const float* __restrict__ a0d, const float* __restrict__ W1,
                            const float* __restrict__ a1s, const float* __restrict__ a1d,
                            _Float16* __restrict__ Wt0, _Float16* __restrict__ Wt1,
                            float* __restrict__ w128row1) {
    const int SEG = 144 * 128;
    int i = blockIdx.x * blockDim.x + threadIdx.x;
    if (i < 2 * SEG) {
        int l = i / SEG;
        int ii = i - l * SEG;
        int n = ii >> 7, k = ii & 127;
        const float* W = l ? W1 : W0;
        const float* as = l ? a1s : a0s;
        const float* ad = l ? a1d : a0d;
        float v = 0.f;
        if (n < 129) v = W[k * MID + n];
        else if (n < 132) {
            int h = n - 129;
            float sum = 0.f;
            for (int c = 0; c < 43; ++c) sum += W[k * MID + 43 * h + c] * as[43 * h + c];
            v = sum;
        } else if (n < 135) {
            int h = n - 132;
            float sum = 0.f;
            for (int c = 0; c < 43; ++c) sum += W[k * MID + 43 * h + c] * ad[43 * h + c];
            v = sum;
        }
        (l ? Wt1 : Wt0)[ii] = (_Float16)v;
    } else if (i < 2 * SEG + 144) {
        int n = i - 2 * SEG;
        float v = 0.f;
        if (n < 129) v = W1[128 * MID + n];
        else if (n < 132) {
            int h = n - 129;
            float sum = 0.f;
            for (int c = 0; c < 43; ++c) sum += W1[128 * MID + 43 * h + c] * a1s[43 * h + c];
            v = sum;
        } else if (n < 135) {
            int h = n - 132;
            float sum = 0.f;
            for (int c = 0; c < 43; ++c) sum += W1[128 * MID + 43 * h + c] * a1d[43 * h + c];
            v = sum;
        }
        w128row1[n] = v;
    }
}

// ---------------- MFMA GEMM + fused logits ----------------
template <bool RANK1>
__global__ __launch_bounds__(256)
void gemm_mfma_kernel(const _Float16* __restrict__ Xh, const float* __restrict__ Xl,
                      const _Float16* __restrict__ Wt, const float* __restrict__ w128,
                      _Float16* __restrict__ Hm16, float* __restrict__ Hl,
                      float* __restrict__ al, float* __restrict__ ar) {
    int wave = threadIdx.x >> 6, lane = threadIdx.x & 63;
    int mt = blockIdx.x * 4 + wave;
    if (mt * 16 >= N_NODES) return;
    int t = lane & 15, quad = lane >> 4;
    int row0 = mt * 16;

    const _Float16* arow = Xh + ((size_t)(row0 + t) << 7) + quad * 8;
    half8 af[4];
#pragma unroll
    for (int kt = 0; kt < 4; ++kt) af[kt] = *(const half8*)(arow + kt * 32);

    floatx4 acc[3];
#pragma unroll
    for (int nt = 0; nt < 3; ++nt) {
        int ntile = blockIdx.y * 3 + nt;
        const _Float16* brow = Wt + ((size_t)(ntile * 16 + t) << 7) + quad * 8;
        floatx4 a = {0.f, 0.f, 0.f, 0.f};
#pragma unroll
        for (int kt = 0; kt < 4; ++kt) {
            half8 b = *(const half8*)(brow + kt * 32);
            a = __builtin_amdgcn_mfma_f32_16x16x32_f16(af[kt], b, a, 0, 0, 0);
        }
        acc[nt] = a;
    }

#pragma unroll
    for (int r = 0; r < 4; ++r) {
        int row = row0 + quad * 4 + r;
        float xl = RANK1 ? Xl[row] : 0.f;
#pragma unroll
        for (int nt = 0; nt < 3; ++nt) {
            int n = (blockIdx.y * 3 + nt) * 16 + t;
            float v = acc[nt][r];
            if (RANK1) v += xl * w128[n];
            if (n < 128) {
                Hm16[((size_t)row << 7) + n] = (_Float16)v;
            } else if (n == 128) {
                Hl[row] = v;
            } else if (n < 132) {
                al[row * 3 + (n - 129)] = v;
            } else if (n < 135) {
                ar[row * 3 + (n - 132)] = v;
            }
        }
    }
}

// ------- fused softmax + aggregation (129 ch, 3 heads), 4 edges/iter, fp16 gathers -------
template <bool ACT>
__global__ void agg129_kernel(const _Float16* __restrict__ Hm16, const float* __restrict__ Hl,
                              const float* __restrict__ al, const float* __restrict__ ar,
                              const int* __restrict__ rowp, const unsigned short* __restrict__ srcs,
                              const float* __restrict__ bias, _Float16* __restrict__ Omh,
                              float* __restrict__ Ol) {
    __shared__ float4 exs[4][64];
    int lane = threadIdx.x & 63;
    int wv   = threadIdx.x >> 6;
    int wid  = blockIdx.x * 4 + wv;
    if (wid >= N_NODES) return;

    int beg = rowp[wid], end = rowp[wid + 1];
    float ard0 = ar[wid * 3], ard1 = ar[wid * 3 + 1], ard2 = ar[wid * 3 + 2];

    int g  = lane >> 4;
    int q  = lane & 15;
    int cb = 8 * q;

    bool bm0[8], bm1[8];
#pragma unroll
    for (int j = 0; j < 8; ++j) {
        bm0[j] = (cb + j) < 43;
        bm1[j] = (cb + j) < 86;
    }

    float accv[8];
#pragma unroll
    for (int j = 0; j < 8; ++j) accv[j] = 0.f;
    float acc128 = 0.f;
    float s0 = 0.f, s1 = 0.f, s2 = 0.f;
    float4* exw = exs[wv];

    for (int base = beg; base < end; base += 64) {
        int i = base + lane;
        float e0 = 0.f, e1 = 0.f, e2 = 0.f;
        int s = 0;
        if (i < end) {
            s = (int)srcs[i];
            const float* ap = al + s * 3;
            e0 = __expf(lrelu(ap[0] + ard0));
            e1 = __expf(lrelu(ap[1] + ard1));
            e2 = __expf(lrelu(ap[2] + ard2));
            s0 += e0; s1 += e1; s2 += e2;
        }
        exw[lane] = make_float4(e0, e1, e2, __int_as_float(s));
        int cnt = end - base; if (cnt > 64) cnt = 64;
        for (int tt = 0; tt < cnt; tt += 4) {
            float4 ed = exw[tt + g];
            int ss = __float_as_int(ed.w);
            half8 hv = *(const half8*)(Hm16 + ((size_t)ss << 7) + cb);
            if (q == 0) acc128 += ed.z * Hl[ss];
#pragma unroll
            for (int j = 0; j < 8; ++j) {
                float w = bm0[j] ? ed.x : (bm1[j] ? ed.y : ed.z);
                accv[j] += w * (float)hv[j];
            }
        }
    }
#pragma unroll
    for (int off = 16; off <= 32; off <<= 1) {
#pragma unroll
        for (int j = 0; j < 8; ++j) accv[j] += __shfl_xor(accv[j], off, 64);
        acc128 += __shfl_xor(acc128, off, 64);
    }
#pragma unroll
    for (int off = 32; off; off >>= 1) {
        s0 += __shfl_xor(s0, off, 64);
        s1 += __shfl_xor(s1, off, 64);
        s2 += __shfl_xor(s2, off, 64);
    }
    float d0 = 1.f / (s0 + 1e-16f);
    float d1 = 1.f / (s1 + 1e-16f);
    float d2 = 1.f / (s2 + 1e-16f);
    if (g == 0) {
        float4 bv0 = *(const float4*)(bias + cb);
        float4 bv1 = *(const float4*)(bias + cb + 4);
        float bb[8] = {bv0.x, bv0.y, bv0.z, bv0.w, bv1.x, bv1.y, bv1.z, bv1.w};
        half8 oh;
#pragma unroll
        for (int j = 0; j < 8; ++j) {
            float dv = bm0[j] ? d0 : (bm1[j] ? d1 : d2);
            float o = accv[j] * dv + bb[j];
            if (ACT) o = lrelu(o);
            oh[j] = (_Float16)o;
        }
        *(half8*)(Omh + ((size_t)wid << 7) + cb) = oh;
        if (lane == 0) {
            float o128 = acc128 * d2 + bias[128];
            if (ACT) o128 = lrelu(o128);
            Ol[wid] = o128;
        }
    }
}

// ---------------- layer 2: fused GEMM (129->6) + logits, wave per node ----------------
__global__ void layer2_node_kernel(const _Float16* __restrict__ Omh, const float* __restrict__ Ol,
                                   const float* __restrict__ W2, const float* __restrict__ a2s,
                                   const float* __restrict__ a2d, float* __restrict__ H2,
                                   float* __restrict__ al2, float* __restrict__ ar2) {
    int lane = threadIdx.x & 63;
    int wid  = blockIdx.x * 4 + (threadIdx.x >> 6);
    if (wid >= N_NODES) return;
    int c0 = 2 * lane;
    half2v xv = *(const half2v*)(Omh + ((size_t)wid << 7) + c0);
    float xx = (float)xv[0], xy = (float)xv[1];
    float x128 = Ol[wid];
    const float* w0p = W2 + c0 * OUTC;
    const float* w1p = W2 + (c0 + 1) * OUTC;
    float m = (lane == 0) ? x128 : 0.f;
    float p[OUTC];
#pragma unroll
    for (int c = 0; c < OUTC; ++c)
        p[c] = xx * w0p[c] + xy * w1p[c] + m * W2[128 * OUTC + c];
#pragma unroll
    for (int off = 32; off; off >>= 1)
#pragma unroll
        for (int c = 0; c < OUTC; ++c) p[c] += __shfl_xor(p[c], off, 64);
    float sl = 0.f, sr = 0.f;
#pragma unroll
    for (int c = 0; c < OUTC; ++c) { sl += p[c] * a2s[c]; sr += p[c] * a2d[c]; }
    if (lane == 0) {
#pragma unroll
        for (int c = 0; c < OUTC; ++c) H2[wid * OUTC + c] = p[c];
        al2[wid] = sl;
        ar2[wid] = sr;
    }
}

// ---------------- layer 2 aggregate (1 head, 6 ch), 8 edges/iter ----------------
__global__ void agg6_kernel(const float* __restrict__ H2, const float* __restrict__ al2,
                            const float* __restrict__ ar2, const int* __restrict__ rowp,
                            const unsigned short* __restrict__ srcs, const float* __restrict__ b2,
                            float* __restrict__ out) {
    __shared__ float2 exs[4][64];
    int lane = threadIdx.x & 63;
    int wv   = threadIdx.x >> 6;
    int wid  = blockIdx.x * 4 + wv;
    if (wid >= N_NODES) return;
    int beg = rowp[wid], end = rowp[wid + 1];
    float ard = ar2[wid];
    int grp = lane >> 3;
    int myc = lane & 7;
    int cc  = (myc < OUTC) ? myc : 0;
    float ssum = 0.f, acc = 0.f;
    float2* exw = exs[wv];
    for (int base = beg; base < end; base += 64) {
        int i = base + lane;
        float ex = 0.f;
        int s = 0;
        if (i < end) {
            s = (int)srcs[i];
            ex = __expf(lrelu(al2[s] + ard));
            ssum += ex;
        }
        exw[lane] = make_float2(ex, __int_as_float(s));
        int cnt = end - base; if (cnt > 64) cnt = 64;
        for (int t = 0; t < cnt; t += 8) {
            float2 ed = exw[t + grp];
            int ss = __float_as_int(ed.y);
            acc += ed.x * H2[ss * OUTC + cc];
        }
    }
    acc += __shfl_xor(acc, 8, 64);
    acc += __shfl_xor(acc, 16, 64);
    acc += __shfl_xor(acc, 32, 64);
#pragma unroll
    for (int off = 32; off; off >>= 1) ssum += __shfl_xor(ssum, off, 64);
    float dinv = 1.f / (ssum + 1e-16f);
    if (lane < OUTC) out[(size_t)wid * OUTC + lane] = acc * dinv + b2[lane];
}

// ---------------- launch ----------------

extern "C" void kernel_launch(void* const* d_in, const int* in_sizes, int n_in,
                              void* d_out, int out_size, void* d_ws, size_t ws_size,
                              hipStream_t stream) {
    const float* x   = (const float*)d_in[0];
    const int*   ei  = (const int*)d_in[1];
    const float* W0  = (const float*)d_in[2];
    const float* a0s = (const float*)d_in[3];
    const float* a0d = (const float*)d_in[4];
    const float* b0  = (const float*)d_in[5];
    const float* W1  = (const float*)d_in[6];
    const float* a1s = (const float*)d_in[7];
    const float* a1d = (const float*)d_in[8];
    const float* b1  = (const float*)d_in[9];
    const float* W2  = (const float*)d_in[10];
    const float* a2s = (const float*)d_in[11];
    const float* a2d = (const float*)d_in[12];
    const float* b2  = (const float*)d_in[13];
    float* out = (float*)d_out;

    char* p = (char*)d_ws;
    auto take = [&](size_t bytes) -> void* {
        void* r = (void*)p;
        p += (bytes + 255) & ~(size_t)255;
        return r;
    };
    int*            ccnt     = (int*)take((size_t)NB * 4);
    int*            cbase    = (int*)take((size_t)(NB + 1) * 4);
    int*            ccur     = (int*)take((size_t)NB * 4);
    unsigned int*   cval     = (unsigned int*)take((size_t)ET * 4);
    int*            rowp     = (int*)take((size_t)(N_NODES + 1) * 4);
    unsigned short* csr_src  = (unsigned short*)take((size_t)ET * 2);
    float*          al       = (float*)take((size_t)N_NODES * 3 * 4);
    float*          ar       = (float*)take((size_t)N_NODES * 3 * 4);
    _Float16*       Xh16     = (_Float16*)take((size_t)N_NODES * 128 * 2);
    _Float16*       Hm16     = (_Float16*)take((size_t)N_NODES * 128 * 2);
    _Float16*       Omh      = (_Float16*)take((size_t)N_NODES * 128 * 2);
    float*          Hl       = (float*)take((size_t)N_NODES * 4);
    float*          Ol       = (float*)take((size_t)N_NODES * 4);
    _Float16*       Wt0      = (_Float16*)take((size_t)144 * 128 * 2);
    _Float16*       Wt1      = (_Float16*)take((size_t)144 * 128 * 2);
    float*          w128row1 = (float*)take((size_t)144 * 4);
    float*          H2       = (float*)take((size_t)N_NODES * OUTC * 4);

    const int* esrc = ei;
    const int* edst = ei + N_EDGES;

    // CSR build (two-phase bin sort)
    hipMemsetAsync(ccnt, 0, (size_t)NB * 4, stream);
    const int cgrid = (ET + CT - 1) / CT;
    ccount_kernel<<<cgrid, 256, 0, stream>>>(edst, ccnt);
    cscan_kernel<<<1, 256, 0, stream>>>(ccnt, cbase, ccur);
    cscatter_kernel<<<cgrid, 256, 0, stream>>>(esrc, edst, ccur, cval);
    fine_kernel<<<NB, 512, 0, stream>>>(cval, cbase, rowp, csr_src);

    // preprocessing for MFMA gemms
    convx_kernel<<<(N_NODES * 128 / 8 + 255) / 256, 256, 0, stream>>>(x, Xh16);
    padw_kernel<<<(2 * 144 * 128 + 144 + 255) / 256, 256, 0, stream>>>(
        W0, a0s, a0d, W1, a1s, a1d, Wt0, Wt1, w128row1);

    const dim3 gemm_grid((N_NODES / 16 + 3) / 4, 3);
    const int  node_grid = (N_NODES + 3) / 4;

    // layer 0
    gemm_mfma_kernel<false><<<gemm_grid, 256, 0, stream>>>(Xh16, Ol, Wt0, w128row1, Hm16, Hl, al, ar);
    agg129_kernel<true><<<node_grid, 256, 0, stream>>>(Hm16, Hl, al, ar, rowp, csr_src, b0, Omh, Ol);

    // layer 1
    gemm_mfma_kernel<true><<<gemm_grid, 256, 0, stream>>>(Omh, Ol, Wt1, w128row1, Hm16, Hl, al, ar);
    agg129_kernel<true><<<node_grid, 256, 0, stream>>>(Hm16, Hl, al, ar, rowp, csr_src, b1, Omh, Ol);

    // layer 2
    layer2_node_kernel<<<node_grid, 256, 0, stream>>>(Omh, Ol, W2, a2s, a2d, H2, al, ar);
    agg6_kernel<<<node_grid, 256, 0, stream>>>(H2, al, ar, rowp, csr_src, b2, out);
}